// Round 1
// baseline (954.350 us; speedup 1.0000x reference)
//
#include <hip/hip_runtime.h>
#include <math.h>

// ---------------------------------------------------------------------------
// Mamba forward, fp32 baseline.
// Shapes: B=8 L=1024 ENC=32 DM=256 DI=512 DS=16 DC=4 DTR=16 LAYERS=2 DFF=1024
// ---------------------------------------------------------------------------

static constexpr int L_SEQ = 1024;
static constexpr int M_ROWS = 8 * 1024;   // B*L

__device__ __forceinline__ float silu_f(float x) { return x / (1.f + __expf(-x)); }
__device__ __forceinline__ float softplus_f(float x) {
  return (x > 20.f) ? x : log1pf(__expf(x));
}

// ---------------------------------------------------------------------------
// Generic NT SGEMM: C[m,n] = epi( sum_k A[m,k]*W[n,k] )
// AMODE: 0 plain A; 1 A[m,k]*silu(Z[m,k]) (out_proj fusion)
// EPI:   0 none; 1 +bias; 2 softplus(+bias)
// M assumed multiple of BM, K multiple of BK. N guarded.
// ---------------------------------------------------------------------------
template<int BM,int BN,int BK,int TM,int TN,int AMODE,int EPI>
__global__ __launch_bounds__((BM/TM)*(BN/TN))
void sgemm_nt(const float* __restrict__ A, int lda,
              const float* __restrict__ Z, int ldz,
              const float* __restrict__ W, int ldw,
              const float* __restrict__ bias,
              float* __restrict__ C, int ldc,
              int N, int K)
{
  constexpr int TX = BN / TN;
  constexpr int TY = BM / TM;
  constexpr int NT = TX * TY;
  constexpr int KQ = BK / 4;          // float4s per k-row
  constexpr int RPP = NT / KQ;        // tile rows loaded per pass

  __shared__ float As[BK][BM + 4];
  __shared__ float Bs[BK][BN + 4];

  const int tid = threadIdx.x;
  const int tx = tid % TX, ty = tid / TX;
  const int bm = blockIdx.x * BM;
  const int bn = blockIdx.y * BN;

  float acc[TM][TN];
#pragma unroll
  for (int i = 0; i < TM; ++i)
#pragma unroll
    for (int j = 0; j < TN; ++j) acc[i][j] = 0.f;

  const int lr = tid / KQ;
  const int lk = (tid % KQ) * 4;

  for (int k0 = 0; k0 < K; k0 += BK) {
#pragma unroll
    for (int r = lr; r < BM; r += RPP) {
      const float* ap = A + (size_t)(bm + r) * lda + k0 + lk;
      float4 v = *reinterpret_cast<const float4*>(ap);
      if (AMODE == 1) {
        const float* zp = Z + (size_t)(bm + r) * ldz + k0 + lk;
        float4 z = *reinterpret_cast<const float4*>(zp);
        v.x *= silu_f(z.x); v.y *= silu_f(z.y);
        v.z *= silu_f(z.z); v.w *= silu_f(z.w);
      }
      As[lk + 0][r] = v.x; As[lk + 1][r] = v.y;
      As[lk + 2][r] = v.z; As[lk + 3][r] = v.w;
    }
#pragma unroll
    for (int r = lr; r < BN; r += RPP) {
      const int n = bn + r;
      float4 v = make_float4(0.f, 0.f, 0.f, 0.f);
      if (n < N) v = *reinterpret_cast<const float4*>(W + (size_t)n * ldw + k0 + lk);
      Bs[lk + 0][r] = v.x; Bs[lk + 1][r] = v.y;
      Bs[lk + 2][r] = v.z; Bs[lk + 3][r] = v.w;
    }
    __syncthreads();
#pragma unroll
    for (int kk = 0; kk < BK; ++kk) {
      float a[TM], b[TN];
#pragma unroll
      for (int i = 0; i < TM; ++i) a[i] = As[kk][ty * TM + i];
#pragma unroll
      for (int j = 0; j < TN; ++j) b[j] = Bs[kk][tx * TN + j];
#pragma unroll
      for (int i = 0; i < TM; ++i)
#pragma unroll
        for (int j = 0; j < TN; ++j) acc[i][j] = fmaf(a[i], b[j], acc[i][j]);
    }
    __syncthreads();
  }

#pragma unroll
  for (int i = 0; i < TM; ++i) {
    const int m = bm + ty * TM + i;
#pragma unroll
    for (int j = 0; j < TN; j += 4) {
      const int n = bn + tx * TN + j;
      if (n >= N) continue;           // N multiple of 4; all-or-nothing per float4
      float4 v;
      float* vv = &v.x;
#pragma unroll
      for (int q = 0; q < 4; ++q) {
        float c = acc[i][j + q];
        if (EPI >= 1) c += bias[n + q];
        if (EPI == 2) c = softplus_f(c);
        vv[q] = c;
      }
      *reinterpret_cast<float4*>(C + (size_t)m * ldc + n) = v;
    }
  }
}

// ---------------------------------------------------------------------------
// Causal depthwise conv (width 4) + bias + silu.  xz(b,l,1024)[:,:,0:512] -> xc(b,l,512)
// ---------------------------------------------------------------------------
__global__ __launch_bounds__(512)
void conv_silu(const float* __restrict__ xz, const float* __restrict__ cw,
               const float* __restrict__ cb, float* __restrict__ xc)
{
  const int b = blockIdx.x;          // 8
  const int l0 = blockIdx.y * 32;    // 32 chunks of 32
  const int d = threadIdx.x;         // 512

  const float w0 = cw[d * 4 + 0], w1 = cw[d * 4 + 1];
  const float w2 = cw[d * 4 + 2], w3 = cw[d * 4 + 3];
  const float bias = cb[d];

  const size_t base = ((size_t)b * L_SEQ) * 1024 + d;
  float xm3 = (l0 >= 3) ? xz[base + (size_t)(l0 - 3) * 1024] : 0.f;
  float xm2 = (l0 >= 2) ? xz[base + (size_t)(l0 - 2) * 1024] : 0.f;
  float xm1 = (l0 >= 1) ? xz[base + (size_t)(l0 - 1) * 1024] : 0.f;

#pragma unroll 4
  for (int i = 0; i < 32; ++i) {
    const int l = l0 + i;
    const float x0 = xz[base + (size_t)l * 1024];
    const float v = bias + w0 * xm3 + w1 * xm2 + w2 * xm1 + w3 * x0;
    xc[((size_t)b * L_SEQ + l) * 512 + d] = silu_f(v);
    xm3 = xm2; xm2 = xm1; xm1 = x0;
  }
}

// ---------------------------------------------------------------------------
// Selective scan. Block = (b, 16 d's) x 256 threads (lane n = tid&15 holds one
// state). LDS-stages 64-timestep chunks of dt/u/B/C; h lives in a register.
// y[b,t,d] = sum_n h*C + u*D.  Writes y (may alias u: chunk staged before store)
// ---------------------------------------------------------------------------
__global__ __launch_bounds__(256)
void scan_kernel(const float* __restrict__ dt, const float* __restrict__ u,
                 const float* __restrict__ xdbl, const float* __restrict__ Alog,
                 const float* __restrict__ Dsk, float* __restrict__ y)
{
  const int b = blockIdx.x;
  const int d0 = blockIdx.y * 16;
  const int tid = threadIdx.x;
  const int n = tid & 15;
  const int dg = tid >> 4;
  const int d = d0 + dg;

  const float Av = -__expf(Alog[d * 16 + n]);
  const float Dv = Dsk[d];
  float h = 0.f;

  __shared__ float sdt[64][16], su[64][16], sB[64][16], sC[64][16], sy[64][16];

  const int lt = tid >> 4;
  const int le = tid & 15;

  for (int c = 0; c < 16; ++c) {
    const int t0 = c * 64;
    __syncthreads();
#pragma unroll
    for (int it = 0; it < 4; ++it) {
      const int t = lt + it * 16;
      const size_t row = (size_t)b * L_SEQ + t0 + t;
      sdt[t][le] = dt[row * 512 + d0 + le];
      su [t][le] = u [row * 512 + d0 + le];
      sB [t][le] = xdbl[row * 48 + 16 + le];
      sC [t][le] = xdbl[row * 48 + 32 + le];
    }
    __syncthreads();
#pragma unroll 16
    for (int t = 0; t < 64; ++t) {
      const float dtv = sdt[t][dg];
      const float uv  = su[t][dg];
      const float dA  = __expf(dtv * Av);
      const float xbu = dtv * uv * sB[t][n];
      h = fmaf(dA, h, xbu);
      float p = h * sC[t][n];
      p += __shfl_xor(p, 1);
      p += __shfl_xor(p, 2);
      p += __shfl_xor(p, 4);
      p += __shfl_xor(p, 8);
      if (n == 0) sy[t][dg] = fmaf(uv, Dv, p);
    }
    __syncthreads();
#pragma unroll
    for (int it = 0; it < 4; ++it) {
      const int t = lt + it * 16;
      y[((size_t)b * L_SEQ + t0 + t) * 512 + d0 + le] = sy[t][le];
    }
  }
}

// ---------------------------------------------------------------------------
// Head: g[b,f] = gelu_exact(h_last[b,:] . p1w[f,:] + p1b[f]); out[b] = g.p2w + p2b
// ---------------------------------------------------------------------------
__global__ __launch_bounds__(256)
void head1(const float* __restrict__ h, const float* __restrict__ p1w,
           const float* __restrict__ p1b, float* __restrict__ g)
{
  const int gid = blockIdx.x * 256 + threadIdx.x;  // 8192 = 1024 f x 8 b
  const int f = gid >> 3;
  const int b = gid & 7;
  const float* hr = h + ((size_t)b * L_SEQ + (L_SEQ - 1)) * 256;
  const float* wr = p1w + (size_t)f * 256;
  float acc = 0.f;
#pragma unroll 8
  for (int k = 0; k < 256; k += 4) {
    float4 hv = *reinterpret_cast<const float4*>(hr + k);
    float4 wv = *reinterpret_cast<const float4*>(wr + k);
    acc = fmaf(hv.x, wv.x, acc); acc = fmaf(hv.y, wv.y, acc);
    acc = fmaf(hv.z, wv.z, acc); acc = fmaf(hv.w, wv.w, acc);
  }
  const float xv = acc + p1b[f];
  g[b * 1024 + f] = 0.5f * xv * (1.f + erff(xv * 0.70710678118654752f));
}

__global__ __launch_bounds__(256)
void head2(const float* __restrict__ g, const float* __restrict__ p2w,
           const float* __restrict__ p2b, float* __restrict__ out)
{
  const int b = blockIdx.x;
  const int tid = threadIdx.x;
  float acc = 0.f;
#pragma unroll
  for (int f = tid; f < 1024; f += 256) acc = fmaf(g[b * 1024 + f], p2w[f], acc);
  acc += __shfl_xor(acc, 1);
  acc += __shfl_xor(acc, 2);
  acc += __shfl_xor(acc, 4);
  acc += __shfl_xor(acc, 8);
  acc += __shfl_xor(acc, 16);
  acc += __shfl_xor(acc, 32);
  __shared__ float red[4];
  if ((tid & 63) == 0) red[tid >> 6] = acc;
  __syncthreads();
  if (tid == 0) out[b] = red[0] + red[1] + red[2] + red[3] + p2b[0];
}

// ---------------------------------------------------------------------------
extern "C" void kernel_launch(void* const* d_in, const int* in_sizes, int n_in,
                              void* d_out, int out_size, void* d_ws, size_t ws_size,
                              hipStream_t stream)
{
  const float* x    = (const float*)d_in[0];
  const float* in_w = (const float*)d_in[1];
  const float* in_b = (const float*)d_in[2];
  const float* ipw  = (const float*)d_in[3];
  const float* cw   = (const float*)d_in[4];
  const float* cb   = (const float*)d_in[5];
  const float* xpw  = (const float*)d_in[6];
  const float* dtw  = (const float*)d_in[7];
  const float* dtb  = (const float*)d_in[8];
  const float* Alog = (const float*)d_in[9];
  const float* Dsk  = (const float*)d_in[10];
  const float* opw  = (const float*)d_in[11];
  const float* p1w  = (const float*)d_in[12];
  const float* p1b  = (const float*)d_in[13];
  const float* p2w  = (const float*)d_in[14];
  const float* p2b  = (const float*)d_in[15];

  float* ws   = (float*)d_ws;
  float* h    = ws;                 // 8192*256   = 2,097,152
  float* xz   = h    + 2097152;     // 8192*1024  = 8,388,608
  float* xc   = xz   + 8388608;     // 8192*512   = 4,194,304
  float* xdbl = xc   + 4194304;     // 8192*48    =   393,216
  float* bdt  = xdbl + 393216;      // 8192*512   = 4,194,304
  float* g    = bdt  + 4194304;     // 8*1024     =     8,192
  float* y    = xc;                 // alias: scan stages chunk to LDS before store
  // total ~77.2 MB

  // embed: h = x @ in_w^T + in_b   (M=8192, N=256, K=32)
  sgemm_nt<32, 64, 16, 4, 4, 0, 1><<<dim3(M_ROWS / 32, 4), 128, 0, stream>>>(
      x, 32, nullptr, 0, in_w, 32, in_b, h, 256, 256, 32);

  for (int layer = 0; layer < 2; ++layer) {
    const float* ipw_l = ipw + (size_t)layer * 1024 * 256;
    const float* cw_l  = cw  + (size_t)layer * 512 * 4;
    const float* cb_l  = cb  + (size_t)layer * 512;
    const float* xpw_l = xpw + (size_t)layer * 48 * 512;
    const float* dtw_l = dtw + (size_t)layer * 512 * 16;
    const float* dtb_l = dtb + (size_t)layer * 512;
    const float* Al_l  = Alog + (size_t)layer * 512 * 16;
    const float* Dsk_l = Dsk + (size_t)layer * 512;
    const float* opw_l = opw + (size_t)layer * 256 * 512;

    // xz = h @ ipw^T   (N=1024, K=256)
    sgemm_nt<128, 128, 16, 8, 8, 0, 0><<<dim3(M_ROWS / 128, 8), 256, 0, stream>>>(
        h, 256, nullptr, 0, ipw_l, 256, nullptr, xz, 1024, 1024, 256);

    // xc = silu(causal_dwconv(xi) + cb)
    conv_silu<<<dim3(8, 32), 512, 0, stream>>>(xz, cw_l, cb_l, xc);

    // xdbl = xc @ xpw^T   (N=48, K=512)
    sgemm_nt<64, 64, 16, 4, 4, 0, 0><<<dim3(M_ROWS / 64, 1), 256, 0, stream>>>(
        xc, 512, nullptr, 0, xpw_l, 512, nullptr, xdbl, 48, 48, 512);

    // dt = softplus(dt_lo @ dtw^T + dtb)   (N=512, K=16, A rows strided 48)
    sgemm_nt<128, 128, 16, 8, 8, 0, 2><<<dim3(M_ROWS / 128, 4), 256, 0, stream>>>(
        xdbl, 48, nullptr, 0, dtw_l, 16, dtb_l, bdt, 512, 512, 16);

    // selective scan -> y (= xc in place), includes +u*D
    scan_kernel<<<dim3(8, 32), 256, 0, stream>>>(bdt, xc, xdbl, Al_l, Dsk_l, y);

    // h = (y * silu(z)) @ opw^T   (N=256, K=512); z = xz[:, 512:]
    sgemm_nt<128, 128, 16, 8, 8, 1, 0><<<dim3(M_ROWS / 128, 2), 256, 0, stream>>>(
        y, 512, xz + 512, 1024, opw_l, 512, nullptr, h, 256, 256, 512);
  }

  head1<<<32, 256, 0, stream>>>(h, p1w, p1b, g);
  head2<<<8, 256, 0, stream>>>(g, p2w, p2b, (float*)d_out);
}

// Round 2
// 813.881 us; speedup vs baseline: 1.1726x; 1.1726x over previous
//
#include <hip/hip_runtime.h>
#include <math.h>

// ---------------------------------------------------------------------------
// Mamba forward, fp32. Round 2: chunked parallel selective scan (16 chunks).
// Shapes: B=8 L=1024 ENC=32 DM=256 DI=512 DS=16 DC=4 DTR=16 LAYERS=2 DFF=1024
// ---------------------------------------------------------------------------

static constexpr int L_SEQ = 1024;
static constexpr int M_ROWS = 8 * 1024;   // B*L
static constexpr int NCHUNK = 16;
static constexpr int TCHUNK = 64;         // L_SEQ / NCHUNK

__device__ __forceinline__ float silu_f(float x) { return x / (1.f + __expf(-x)); }
__device__ __forceinline__ float softplus_f(float x) {
  return (x > 20.f) ? x : log1pf(__expf(x));
}

// ---------------------------------------------------------------------------
// Generic NT SGEMM: C[m,n] = epi( sum_k A[m,k]*W[n,k] )
// AMODE: 0 plain A; 1 A[m,k]*silu(Z[m,k]) (out_proj fusion)
// EPI:   0 none; 1 +bias; 2 softplus(+bias)
// ---------------------------------------------------------------------------
template<int BM,int BN,int BK,int TM,int TN,int AMODE,int EPI>
__global__ __launch_bounds__((BM/TM)*(BN/TN))
void sgemm_nt(const float* __restrict__ A, int lda,
              const float* __restrict__ Z, int ldz,
              const float* __restrict__ W, int ldw,
              const float* __restrict__ bias,
              float* __restrict__ C, int ldc,
              int N, int K)
{
  constexpr int TX = BN / TN;
  constexpr int TY = BM / TM;
  constexpr int NT = TX * TY;
  constexpr int KQ = BK / 4;          // float4s per k-row
  constexpr int RPP = NT / KQ;        // tile rows loaded per pass

  __shared__ float As[BK][BM + 4];
  __shared__ float Bs[BK][BN + 4];

  const int tid = threadIdx.x;
  const int tx = tid % TX, ty = tid / TX;
  const int bm = blockIdx.x * BM;
  const int bn = blockIdx.y * BN;

  float acc[TM][TN];
#pragma unroll
  for (int i = 0; i < TM; ++i)
#pragma unroll
    for (int j = 0; j < TN; ++j) acc[i][j] = 0.f;

  const int lr = tid / KQ;
  const int lk = (tid % KQ) * 4;

  for (int k0 = 0; k0 < K; k0 += BK) {
#pragma unroll
    for (int r = lr; r < BM; r += RPP) {
      const float* ap = A + (size_t)(bm + r) * lda + k0 + lk;
      float4 v = *reinterpret_cast<const float4*>(ap);
      if (AMODE == 1) {
        const float* zp = Z + (size_t)(bm + r) * ldz + k0 + lk;
        float4 z = *reinterpret_cast<const float4*>(zp);
        v.x *= silu_f(z.x); v.y *= silu_f(z.y);
        v.z *= silu_f(z.z); v.w *= silu_f(z.w);
      }
      As[lk + 0][r] = v.x; As[lk + 1][r] = v.y;
      As[lk + 2][r] = v.z; As[lk + 3][r] = v.w;
    }
#pragma unroll
    for (int r = lr; r < BN; r += RPP) {
      const int n = bn + r;
      float4 v = make_float4(0.f, 0.f, 0.f, 0.f);
      if (n < N) v = *reinterpret_cast<const float4*>(W + (size_t)n * ldw + k0 + lk);
      Bs[lk + 0][r] = v.x; Bs[lk + 1][r] = v.y;
      Bs[lk + 2][r] = v.z; Bs[lk + 3][r] = v.w;
    }
    __syncthreads();
#pragma unroll
    for (int kk = 0; kk < BK; ++kk) {
      float a[TM], b[TN];
#pragma unroll
      for (int i = 0; i < TM; ++i) a[i] = As[kk][ty * TM + i];
#pragma unroll
      for (int j = 0; j < TN; ++j) b[j] = Bs[kk][tx * TN + j];
#pragma unroll
      for (int i = 0; i < TM; ++i)
#pragma unroll
        for (int j = 0; j < TN; ++j) acc[i][j] = fmaf(a[i], b[j], acc[i][j]);
    }
    __syncthreads();
  }

#pragma unroll
  for (int i = 0; i < TM; ++i) {
    const int m = bm + ty * TM + i;
#pragma unroll
    for (int j = 0; j < TN; j += 4) {
      const int n = bn + tx * TN + j;
      if (n >= N) continue;           // N multiple of 4; all-or-nothing per float4
      float4 v;
      float* vv = &v.x;
#pragma unroll
      for (int q = 0; q < 4; ++q) {
        float c = acc[i][j + q];
        if (EPI >= 1) c += bias[n + q];
        if (EPI == 2) c = softplus_f(c);
        vv[q] = c;
      }
      *reinterpret_cast<float4*>(C + (size_t)m * ldc + n) = v;
    }
  }
}

// ---------------------------------------------------------------------------
// Causal depthwise conv (width 4) + bias + silu.  xz(b,l,1024)[:,:,0:512] -> xc(b,l,512)
// ---------------------------------------------------------------------------
__global__ __launch_bounds__(512)
void conv_silu(const float* __restrict__ xz, const float* __restrict__ cw,
               const float* __restrict__ cb, float* __restrict__ xc)
{
  const int b = blockIdx.x;          // 8
  const int l0 = blockIdx.y * 32;    // 32 chunks of 32
  const int d = threadIdx.x;         // 512

  const float w0 = cw[d * 4 + 0], w1 = cw[d * 4 + 1];
  const float w2 = cw[d * 4 + 2], w3 = cw[d * 4 + 3];
  const float bias = cb[d];

  const size_t base = ((size_t)b * L_SEQ) * 1024 + d;
  float xm3 = (l0 >= 3) ? xz[base + (size_t)(l0 - 3) * 1024] : 0.f;
  float xm2 = (l0 >= 2) ? xz[base + (size_t)(l0 - 2) * 1024] : 0.f;
  float xm1 = (l0 >= 1) ? xz[base + (size_t)(l0 - 1) * 1024] : 0.f;

#pragma unroll 4
  for (int i = 0; i < 32; ++i) {
    const int l = l0 + i;
    const float x0 = xz[base + (size_t)l * 1024];
    const float v = bias + w0 * xm3 + w1 * xm2 + w2 * xm1 + w3 * x0;
    xc[((size_t)b * L_SEQ + l) * 512 + d] = silu_f(v);
    xm3 = xm2; xm2 = xm1; xm1 = x0;
  }
}

// ---------------------------------------------------------------------------
// Chunked selective scan, pass 1: each block scans TCHUNK=64 timesteps of one
// (b, 16-d group, chunk) with h0=0.  Writes local y (incl. u*D) and per-(d,n)
// chunk aggregates Ac = prod(dA), Bc = final local h.
// Thread layout: 256 = 16 d (tid>>4) x 16 n (tid&15).
// ---------------------------------------------------------------------------
__global__ __launch_bounds__(256)
void scan_part1(const float* __restrict__ dt, const float* __restrict__ u,
                const float* __restrict__ xdbl, const float* __restrict__ Alog,
                const float* __restrict__ Dsk, float* __restrict__ y,
                float* __restrict__ Ac, float* __restrict__ Bc)
{
  const int b = blockIdx.x;
  const int d0 = blockIdx.y * 16;
  const int c = blockIdx.z;
  const int t0 = c * TCHUNK;
  const int tid = threadIdx.x;
  const int n = tid & 15;
  const int dg = tid >> 4;
  const int d = d0 + dg;

  const float Av = -__expf(Alog[d * 16 + n]);
  const float Dv = Dsk[d];

  __shared__ float sdt[TCHUNK][16], su[TCHUNK][16], sB[TCHUNK][16],
                   sC[TCHUNK][16], sy[TCHUNK][16];
  const int lt = tid >> 4;
  const int le = tid & 15;
#pragma unroll
  for (int it = 0; it < 4; ++it) {
    const int t = lt + it * 16;
    const size_t row = (size_t)b * L_SEQ + t0 + t;
    sdt[t][le] = dt[row * 512 + d0 + le];
    su [t][le] = u [row * 512 + d0 + le];
    sB [t][le] = xdbl[row * 48 + 16 + le];
    sC [t][le] = xdbl[row * 48 + 32 + le];
  }
  __syncthreads();

  float h = 0.f, p = 1.f;
#pragma unroll 8
  for (int t = 0; t < TCHUNK; ++t) {
    const float dtv = sdt[t][dg];
    const float uv  = su[t][dg];
    const float dA  = __expf(dtv * Av);
    h = fmaf(dA, h, dtv * uv * sB[t][n]);
    p *= dA;
    float r = h * sC[t][n];
    r += __shfl_xor(r, 1);
    r += __shfl_xor(r, 2);
    r += __shfl_xor(r, 4);
    r += __shfl_xor(r, 8);
    if (n == 0) sy[t][dg] = fmaf(uv, Dv, r);
  }

  const size_t abi = (((size_t)b * NCHUNK + c) * 512 + d) * 16 + n;
  Ac[abi] = p;
  Bc[abi] = h;

  __syncthreads();
#pragma unroll
  for (int it = 0; it < 4; ++it) {
    const int t = lt + it * 16;
    y[((size_t)b * L_SEQ + t0 + t) * 512 + d0 + le] = sy[t][le];
  }
}

// ---------------------------------------------------------------------------
// Chunked scan fixup: for chunk c>=1, compute incoming state
// hin = scan over (Ac,Bc) of chunks 0..c-1, then add y_t += C_t . (P_t * hin)
// where P_t is the running product of dA within the chunk.
// ---------------------------------------------------------------------------
__global__ __launch_bounds__(256)
void scan_fixup(const float* __restrict__ dt, const float* __restrict__ xdbl,
                const float* __restrict__ Alog,
                const float* __restrict__ Ac, const float* __restrict__ Bc,
                float* __restrict__ y)
{
  const int b = blockIdx.x;
  const int d0 = blockIdx.y * 16;
  const int c = blockIdx.z + 1;        // chunks 1..15
  const int t0 = c * TCHUNK;
  const int tid = threadIdx.x;
  const int n = tid & 15;
  const int dg = tid >> 4;
  const int d = d0 + dg;

  const float Av = -__expf(Alog[d * 16 + n]);

  float hin = 0.f;
  for (int cc = 0; cc < c; ++cc) {
    const size_t abi = (((size_t)b * NCHUNK + cc) * 512 + d) * 16 + n;
    hin = fmaf(Ac[abi], hin, Bc[abi]);
  }

  __shared__ float sdt[TCHUNK][16], sC[TCHUNK][16], sy[TCHUNK][16];
  const int lt = tid >> 4;
  const int le = tid & 15;
#pragma unroll
  for (int it = 0; it < 4; ++it) {
    const int t = lt + it * 16;
    const size_t row = (size_t)b * L_SEQ + t0 + t;
    sdt[t][le] = dt[row * 512 + d0 + le];
    sC [t][le] = xdbl[row * 48 + 32 + le];
  }
  __syncthreads();

  float p = 1.f;
#pragma unroll 8
  for (int t = 0; t < TCHUNK; ++t) {
    p *= __expf(sdt[t][dg] * Av);
    float r = p * hin * sC[t][n];
    r += __shfl_xor(r, 1);
    r += __shfl_xor(r, 2);
    r += __shfl_xor(r, 4);
    r += __shfl_xor(r, 8);
    if (n == 0) sy[t][dg] = r;
  }
  __syncthreads();
#pragma unroll
  for (int it = 0; it < 4; ++it) {
    const int t = lt + it * 16;
    const size_t idx = ((size_t)b * L_SEQ + t0 + t) * 512 + d0 + le;
    y[idx] += sy[t][le];
  }
}

// ---------------------------------------------------------------------------
// Head: g[b,f] = gelu_exact(h_last[b,:] . p1w[f,:] + p1b[f]); out[b] = g.p2w + p2b
// ---------------------------------------------------------------------------
__global__ __launch_bounds__(256)
void head1(const float* __restrict__ h, const float* __restrict__ p1w,
           const float* __restrict__ p1b, float* __restrict__ g)
{
  const int gid = blockIdx.x * 256 + threadIdx.x;  // 8192 = 1024 f x 8 b
  const int f = gid >> 3;
  const int b = gid & 7;
  const float* hr = h + ((size_t)b * L_SEQ + (L_SEQ - 1)) * 256;
  const float* wr = p1w + (size_t)f * 256;
  float acc = 0.f;
#pragma unroll 8
  for (int k = 0; k < 256; k += 4) {
    float4 hv = *reinterpret_cast<const float4*>(hr + k);
    float4 wv = *reinterpret_cast<const float4*>(wr + k);
    acc = fmaf(hv.x, wv.x, acc); acc = fmaf(hv.y, wv.y, acc);
    acc = fmaf(hv.z, wv.z, acc); acc = fmaf(hv.w, wv.w, acc);
  }
  const float xv = acc + p1b[f];
  g[b * 1024 + f] = 0.5f * xv * (1.f + erff(xv * 0.70710678118654752f));
}

__global__ __launch_bounds__(256)
void head2(const float* __restrict__ g, const float* __restrict__ p2w,
           const float* __restrict__ p2b, float* __restrict__ out)
{
  const int b = blockIdx.x;
  const int tid = threadIdx.x;
  float acc = 0.f;
#pragma unroll
  for (int f = tid; f < 1024; f += 256) acc = fmaf(g[b * 1024 + f], p2w[f], acc);
  acc += __shfl_xor(acc, 1);
  acc += __shfl_xor(acc, 2);
  acc += __shfl_xor(acc, 4);
  acc += __shfl_xor(acc, 8);
  acc += __shfl_xor(acc, 16);
  acc += __shfl_xor(acc, 32);
  __shared__ float red[4];
  if ((tid & 63) == 0) red[tid >> 6] = acc;
  __syncthreads();
  if (tid == 0) out[b] = red[0] + red[1] + red[2] + red[3] + p2b[0];
}

// ---------------------------------------------------------------------------
extern "C" void kernel_launch(void* const* d_in, const int* in_sizes, int n_in,
                              void* d_out, int out_size, void* d_ws, size_t ws_size,
                              hipStream_t stream)
{
  const float* x    = (const float*)d_in[0];
  const float* in_w = (const float*)d_in[1];
  const float* in_b = (const float*)d_in[2];
  const float* ipw  = (const float*)d_in[3];
  const float* cw   = (const float*)d_in[4];
  const float* cb   = (const float*)d_in[5];
  const float* xpw  = (const float*)d_in[6];
  const float* dtw  = (const float*)d_in[7];
  const float* dtb  = (const float*)d_in[8];
  const float* Alog = (const float*)d_in[9];
  const float* Dsk  = (const float*)d_in[10];
  const float* opw  = (const float*)d_in[11];
  const float* p1w  = (const float*)d_in[12];
  const float* p1b  = (const float*)d_in[13];
  const float* p2w  = (const float*)d_in[14];
  const float* p2b  = (const float*)d_in[15];

  float* ws   = (float*)d_ws;
  float* h    = ws;                 // 8192*256   = 2,097,152
  float* xz   = h    + 2097152;     // 8192*1024  = 8,388,608
  float* xc   = xz   + 8388608;     // 8192*512   = 4,194,304
  float* xdbl = xc   + 4194304;     // 8192*48    =   393,216
  float* bdt  = xdbl + 393216;      // 8192*512   = 4,194,304
  float* g    = bdt  + 4194304;     // 8*1024     =     8,192
  float* y    = xc;                 // alias: scan stages chunk to LDS before store
  // Ac/Bc (8*16*512*16 = 1,048,576 floats each) alias onto h: h's value is
  // dead between the in_proj GEMM (reads h) and the out_proj GEMM (rewrites h),
  // and the scan runs entirely inside that window.
  float* Ac   = h;
  float* Bc   = h + 1048576;
  // total ~77.2 MB (unchanged from round 1)

  // embed: h = x @ in_w^T + in_b   (M=8192, N=256, K=32)
  sgemm_nt<32, 64, 16, 4, 4, 0, 1><<<dim3(M_ROWS / 32, 4), 128, 0, stream>>>(
      x, 32, nullptr, 0, in_w, 32, in_b, h, 256, 256, 32);

  for (int layer = 0; layer < 2; ++layer) {
    const float* ipw_l = ipw + (size_t)layer * 1024 * 256;
    const float* cw_l  = cw  + (size_t)layer * 512 * 4;
    const float* cb_l  = cb  + (size_t)layer * 512;
    const float* xpw_l = xpw + (size_t)layer * 48 * 512;
    const float* dtw_l = dtw + (size_t)layer * 512 * 16;
    const float* dtb_l = dtb + (size_t)layer * 512;
    const float* Al_l  = Alog + (size_t)layer * 512 * 16;
    const float* Dsk_l = Dsk + (size_t)layer * 512;
    const float* opw_l = opw + (size_t)layer * 256 * 512;

    // xz = h @ ipw^T   (N=1024, K=256)
    sgemm_nt<128, 128, 16, 8, 8, 0, 0><<<dim3(M_ROWS / 128, 8), 256, 0, stream>>>(
        h, 256, nullptr, 0, ipw_l, 256, nullptr, xz, 1024, 1024, 256);

    // xc = silu(causal_dwconv(xi) + cb)
    conv_silu<<<dim3(8, 32), 512, 0, stream>>>(xz, cw_l, cb_l, xc);

    // xdbl = xc @ xpw^T   (N=48, K=512)
    sgemm_nt<64, 64, 16, 4, 4, 0, 0><<<dim3(M_ROWS / 64, 1), 256, 0, stream>>>(
        xc, 512, nullptr, 0, xpw_l, 512, nullptr, xdbl, 48, 48, 512);

    // dt = softplus(dt_lo @ dtw^T + dtb)   (N=512, K=16, A rows strided 48)
    sgemm_nt<128, 128, 16, 8, 8, 0, 2><<<dim3(M_ROWS / 128, 4), 256, 0, stream>>>(
        xdbl, 48, nullptr, 0, dtw_l, 16, dtb_l, bdt, 512, 512, 16);

    // chunked selective scan -> y (= xc in place), includes +u*D
    scan_part1<<<dim3(8, 32, NCHUNK), 256, 0, stream>>>(
        bdt, xc, xdbl, Al_l, Dsk_l, y, Ac, Bc);
    scan_fixup<<<dim3(8, 32, NCHUNK - 1), 256, 0, stream>>>(
        bdt, xdbl, Al_l, Ac, Bc, y);

    // h = (y * silu(z)) @ opw^T   (N=256, K=512); z = xz[:, 512:]
    sgemm_nt<128, 128, 16, 8, 8, 1, 0><<<dim3(M_ROWS / 128, 2), 256, 0, stream>>>(
        y, 512, xz + 512, 1024, opw_l, 512, nullptr, h, 256, 256, 512);
  }

  head1<<<32, 256, 0, stream>>>(h, p1w, p1b, g);
  head2<<<8, 256, 0, stream>>>(g, p2w, p2b, (float*)d_out);
}

// Round 4
// 551.763 us; speedup vs baseline: 1.7296x; 1.4751x over previous
//
#include <hip/hip_runtime.h>
#include <math.h>

// ---------------------------------------------------------------------------
// Mamba forward. Round 4: bf16 MFMA GEMMs (fp32 accumulate). fp16 failed from
// DENORMAL UNDERFLOW (layer-2 activations ~1e-7..1e-13 < f16 min denormal 6e-8
// -> exact-zero output). bf16 has fp32 exponent range: no underflow, 0.2%/cast.
// Embed GEMM + head kept fp32 (cheap, saves rounding stages). Scan fp32.
// Shapes: B=8 L=1024 ENC=32 DM=256 DI=512 DS=16 DC=4 DTR=16 LAYERS=2 DFF=1024
// ---------------------------------------------------------------------------

static constexpr int L_SEQ = 1024;
static constexpr int M_ROWS = 8 * 1024;   // B*L
static constexpr int NCHUNK = 16;
static constexpr int TCHUNK = 64;         // L_SEQ / NCHUNK

typedef unsigned short u16;
typedef unsigned short u16x8 __attribute__((ext_vector_type(8)));
typedef short bf16x8 __attribute__((ext_vector_type(8)));   // MFMA operand type
typedef float f32x4 __attribute__((ext_vector_type(4)));

__device__ __forceinline__ float silu_f(float x) { return x / (1.f + __expf(-x)); }
__device__ __forceinline__ float softplus_f(float x) {
  return (x > 20.f) ? x : log1pf(__expf(x));
}
__device__ __forceinline__ u16 f2bf(float f) {          // RNE fp32->bf16
  unsigned u = __builtin_bit_cast(unsigned, f);
  u += 0x7FFFu + ((u >> 16) & 1u);
  return (u16)(u >> 16);
}
__device__ __forceinline__ float bf2f(u16 v) {
  return __builtin_bit_cast(float, (unsigned)v << 16);
}
__device__ __forceinline__ u16x8 cvt8(const float* p) { // 8 fp32 -> 8 bf16
  float4 a = *reinterpret_cast<const float4*>(p);
  float4 b = *reinterpret_cast<const float4*>(p + 4);
  u16x8 v;
  v[0] = f2bf(a.x); v[1] = f2bf(a.y); v[2] = f2bf(a.z); v[3] = f2bf(a.w);
  v[4] = f2bf(b.x); v[5] = f2bf(b.y); v[6] = f2bf(b.z); v[7] = f2bf(b.w);
  return v;
}

// ---------------------------------------------------------------------------
// bf16 MFMA GEMM:  C[m,n] = epi( sum_k A[m,k] * W[n,k] ), fp32 accumulate.
// 256 threads = 4 waves (WR x WC). MFMA 16x16x32_bf16, BK=32.
// AMODE: 0 A fp32 (cast); 1 A bf16; 2 A bf16 * silu(Z bf16)
// WBF:   0 W fp32 (cast); 1 W bf16
// EPI:   0 none; 1 +bias; 2 combo: n<512 -> softplus(c+bias[n]), else raw
// OUTBF: output bf16 else fp32
// Fragment layouts (verified, learn_hip m89/m120):
//   A-op: lane holds A[m=lane&15][k=(lane>>4)*8+j]
//   B-op: lane holds B[k=(lane>>4)*8+j][n=lane&15]  (= W[n][k], W row-major NxK)
//   C/D:  col=lane&15, row=(lane>>4)*4+reg
// ---------------------------------------------------------------------------
template<int BM,int BN,int WR,int WC,int AMODE,int WBF,int EPI,int OUTBF>
__global__ __launch_bounds__(256)
void gemm_bf(const void* __restrict__ Ap, int lda,
             const void* __restrict__ Zp, int ldz,
             const void* __restrict__ Wp, int ldw,
             const float* __restrict__ bias,
             void* __restrict__ Cp, int ldc,
             int N, int K)
{
  constexpr int SK = 40;                  // LDS stride (bf16): 32 + 8 pad
  constexpr int TI = BM / WR / 16;
  constexpr int TJ = BN / WC / 16;

  __shared__ u16 As[BM * SK];
  __shared__ u16 Ws[BN * SK];

  const int tid = threadIdx.x;
  const int bm = blockIdx.x * BM;
  const int bn = blockIdx.y * BN;
  const int lane = tid & 63;
  const int wv = tid >> 6;
  const int wy = wv / WC, wx = wv % WC;
  const int rb = wy * (BM / WR);
  const int cb = wx * (BN / WC);
  const int lr = lane & 15, lq = lane >> 4;

  f32x4 acc[TI][TJ];
#pragma unroll
  for (int i = 0; i < TI; ++i)
#pragma unroll
    for (int j = 0; j < TJ; ++j) acc[i][j] = (f32x4){0.f, 0.f, 0.f, 0.f};

  for (int k0 = 0; k0 < K; k0 += 32) {
    // ---- stage A tile (BM x 32 bf16), chunks of 8 ----
#pragma unroll
    for (int c = tid; c < BM * 4; c += 256) {
      const int r = c >> 2, kh = (c & 3) * 8;
      u16x8 v;
      if (AMODE == 0) {
        v = cvt8((const float*)Ap + (size_t)(bm + r) * lda + k0 + kh);
      } else {
        v = *reinterpret_cast<const u16x8*>(
              (const u16*)Ap + (size_t)(bm + r) * lda + k0 + kh);
        if (AMODE == 2) {
          u16x8 z = *reinterpret_cast<const u16x8*>(
                      (const u16*)Zp + (size_t)(bm + r) * ldz + k0 + kh);
#pragma unroll
          for (int j = 0; j < 8; ++j)
            v[j] = f2bf(bf2f(v[j]) * silu_f(bf2f(z[j])));
        }
      }
      *reinterpret_cast<u16x8*>(&As[r * SK + kh]) = v;
    }
    // ---- stage W tile (BN x 32 bf16) ----
#pragma unroll
    for (int c = tid; c < BN * 4; c += 256) {
      const int r = c >> 2, kh = (c & 3) * 8;
      const int n = bn + r;
      u16x8 v = (u16x8){0,0,0,0,0,0,0,0};
      if (n < N) {
        if (WBF) v = *reinterpret_cast<const u16x8*>(
                       (const u16*)Wp + (size_t)n * ldw + k0 + kh);
        else     v = cvt8((const float*)Wp + (size_t)n * ldw + k0 + kh);
      }
      *reinterpret_cast<u16x8*>(&Ws[r * SK + kh]) = v;
    }
    __syncthreads();

    bf16x8 af[TI], bf[TJ];
#pragma unroll
    for (int i = 0; i < TI; ++i)
      af[i] = *reinterpret_cast<const bf16x8*>(&As[(rb + i * 16 + lr) * SK + lq * 8]);
#pragma unroll
    for (int j = 0; j < TJ; ++j)
      bf[j] = *reinterpret_cast<const bf16x8*>(&Ws[(cb + j * 16 + lr) * SK + lq * 8]);
#pragma unroll
    for (int i = 0; i < TI; ++i)
#pragma unroll
      for (int j = 0; j < TJ; ++j)
        acc[i][j] = __builtin_amdgcn_mfma_f32_16x16x32_bf16(af[i], bf[j], acc[i][j], 0, 0, 0);
    __syncthreads();
  }

  // ---- epilogue ----
#pragma unroll
  for (int i = 0; i < TI; ++i) {
#pragma unroll
    for (int j = 0; j < TJ; ++j) {
      const int col = bn + cb + j * 16 + lr;
      if (col >= N) continue;
#pragma unroll
      for (int r = 0; r < 4; ++r) {
        const int row = bm + rb + i * 16 + lq * 4 + r;
        float c = acc[i][j][r];
        if (EPI == 1) c += bias[col];
        if (EPI == 2) { if (col < 512) c = softplus_f(c + bias[col]); }
        if (OUTBF) ((u16*)Cp)[(size_t)row * ldc + col] = f2bf(c);
        else       ((float*)Cp)[(size_t)row * ldc + col] = c;
      }
    }
  }
}

// ---------------------------------------------------------------------------
// fp32 SGEMM (embed only: M=8192, N=256, K=32 — keeps one rounding stage out)
// ---------------------------------------------------------------------------
template<int BM,int BN,int BK,int TM,int TN>
__global__ __launch_bounds__((BM/TM)*(BN/TN))
void sgemm_nt(const float* __restrict__ A, int lda,
              const float* __restrict__ W, int ldw,
              const float* __restrict__ bias,
              float* __restrict__ C, int ldc, int N, int K)
{
  constexpr int TX = BN / TN;
  constexpr int TY = BM / TM;
  constexpr int NT = TX * TY;
  constexpr int KQ = BK / 4;
  constexpr int RPP = NT / KQ;

  __shared__ float As[BK][BM + 4];
  __shared__ float Bs[BK][BN + 4];

  const int tid = threadIdx.x;
  const int tx = tid % TX, ty = tid / TX;
  const int bm = blockIdx.x * BM;
  const int bn = blockIdx.y * BN;

  float acc[TM][TN];
#pragma unroll
  for (int i = 0; i < TM; ++i)
#pragma unroll
    for (int j = 0; j < TN; ++j) acc[i][j] = 0.f;

  const int lr = tid / KQ;
  const int lk = (tid % KQ) * 4;

  for (int k0 = 0; k0 < K; k0 += BK) {
#pragma unroll
    for (int r = lr; r < BM; r += RPP) {
      float4 v = *reinterpret_cast<const float4*>(A + (size_t)(bm + r) * lda + k0 + lk);
      As[lk + 0][r] = v.x; As[lk + 1][r] = v.y;
      As[lk + 2][r] = v.z; As[lk + 3][r] = v.w;
    }
#pragma unroll
    for (int r = lr; r < BN; r += RPP) {
      float4 v = *reinterpret_cast<const float4*>(W + (size_t)(bn + r) * ldw + k0 + lk);
      Bs[lk + 0][r] = v.x; Bs[lk + 1][r] = v.y;
      Bs[lk + 2][r] = v.z; Bs[lk + 3][r] = v.w;
    }
    __syncthreads();
#pragma unroll
    for (int kk = 0; kk < BK; ++kk) {
      float a[TM], b[TN];
#pragma unroll
      for (int i = 0; i < TM; ++i) a[i] = As[kk][ty * TM + i];
#pragma unroll
      for (int j = 0; j < TN; ++j) b[j] = Bs[kk][tx * TN + j];
#pragma unroll
      for (int i = 0; i < TM; ++i)
#pragma unroll
        for (int j = 0; j < TN; ++j) acc[i][j] = fmaf(a[i], b[j], acc[i][j]);
    }
    __syncthreads();
  }
#pragma unroll
  for (int i = 0; i < TM; ++i) {
    const int m = bm + ty * TM + i;
#pragma unroll
    for (int j = 0; j < TN; j += 4) {
      const int n = bn + tx * TN + j;
      float4 v;
      v.x = acc[i][j + 0] + bias[n + 0];
      v.y = acc[i][j + 1] + bias[n + 1];
      v.z = acc[i][j + 2] + bias[n + 2];
      v.w = acc[i][j + 3] + bias[n + 3];
      *reinterpret_cast<float4*>(C + (size_t)m * ldc + n) = v;
    }
  }
}

// ---------------------------------------------------------------------------
// W_combo precompute: rows 0..511 = dtw(512x16) . xpw[0:16,:] (dt folded),
// rows 512..527 = xpw[16:32,:] (B), rows 528..543 = xpw[32:48,:] (C). bf16 out.
// ---------------------------------------------------------------------------
__global__ __launch_bounds__(512)
void wprep(const float* __restrict__ dtw, const float* __restrict__ xpw,
           u16* __restrict__ wc)
{
  const int layer = blockIdx.y;
  const int n = blockIdx.x;      // 0..543
  const int k = threadIdx.x;     // 0..511
  const float* xp = xpw + (size_t)layer * 48 * 512;
  float v;
  if (n < 512) {
    const float* dw = dtw + (size_t)layer * 512 * 16 + n * 16;
    v = 0.f;
#pragma unroll
    for (int r = 0; r < 16; ++r) v = fmaf(dw[r], xp[r * 512 + k], v);
  } else {
    v = xp[(16 + (n - 512)) * 512 + k];
  }
  wc[((size_t)layer * 544 + n) * 512 + k] = f2bf(v);
}

// ---------------------------------------------------------------------------
// Causal depthwise conv (width 4) + bias + silu. xz bf16 (b,l,1024)[:,:512] -> xc bf16
// ---------------------------------------------------------------------------
__global__ __launch_bounds__(512)
void conv_silu(const u16* __restrict__ xz, const float* __restrict__ cw,
               const float* __restrict__ cb, u16* __restrict__ xc)
{
  const int b = blockIdx.x;          // 8
  const int l0 = blockIdx.y * 32;    // 32 chunks of 32
  const int d = threadIdx.x;         // 512

  const float w0 = cw[d * 4 + 0], w1 = cw[d * 4 + 1];
  const float w2 = cw[d * 4 + 2], w3 = cw[d * 4 + 3];
  const float bias = cb[d];

  const size_t base = ((size_t)b * L_SEQ) * 1024 + d;
  float xm3 = (l0 >= 3) ? bf2f(xz[base + (size_t)(l0 - 3) * 1024]) : 0.f;
  float xm2 = (l0 >= 2) ? bf2f(xz[base + (size_t)(l0 - 2) * 1024]) : 0.f;
  float xm1 = (l0 >= 1) ? bf2f(xz[base + (size_t)(l0 - 1) * 1024]) : 0.f;

#pragma unroll 4
  for (int i = 0; i < 32; ++i) {
    const int l = l0 + i;
    const float x0 = bf2f(xz[base + (size_t)l * 1024]);
    const float v = bias + w0 * xm3 + w1 * xm2 + w2 * xm1 + w3 * x0;
    xc[((size_t)b * L_SEQ + l) * 512 + d] = f2bf(silu_f(v));
    xm3 = xm2; xm2 = xm1; xm1 = x0;
  }
}

// ---------------------------------------------------------------------------
// Chunked selective scan pass 1. xo rows (stride 544 f32): [0:512)=dt(softplus'd),
// [512:528)=B, [528:544)=C. u bf16 (stride 512). y bf16 out (aliases u: chunk
// staged to LDS before store). Block = (b, 16 d's, chunk) x 256 threads.
// ---------------------------------------------------------------------------
__global__ __launch_bounds__(256)
void scan_part1(const float* __restrict__ xo, const u16* __restrict__ u,
                const float* __restrict__ Alog, const float* __restrict__ Dsk,
                u16* __restrict__ y, float* __restrict__ Ac, float* __restrict__ Bc)
{
  const int b = blockIdx.x;
  const int d0 = blockIdx.y * 16;
  const int c = blockIdx.z;
  const int t0 = c * TCHUNK;
  const int tid = threadIdx.x;
  const int n = tid & 15;
  const int dg = tid >> 4;
  const int d = d0 + dg;

  const float Av = -__expf(Alog[d * 16 + n]);
  const float Dv = Dsk[d];

  __shared__ float sdt[TCHUNK][16], su[TCHUNK][16], sB[TCHUNK][16],
                   sC[TCHUNK][16], sy[TCHUNK][16];
  const int lt = tid >> 4;
  const int le = tid & 15;
#pragma unroll
  for (int it = 0; it < 4; ++it) {
    const int t = lt + it * 16;
    const size_t row = (size_t)b * L_SEQ + t0 + t;
    sdt[t][le] = xo[row * 544 + d0 + le];
    su [t][le] = bf2f(u[row * 512 + d0 + le]);
    sB [t][le] = xo[row * 544 + 512 + le];
    sC [t][le] = xo[row * 544 + 528 + le];
  }
  __syncthreads();

  float h = 0.f, p = 1.f;
#pragma unroll 8
  for (int t = 0; t < TCHUNK; ++t) {
    const float dtv = sdt[t][dg];
    const float uv  = su[t][dg];
    const float dA  = __expf(dtv * Av);
    h = fmaf(dA, h, dtv * uv * sB[t][n]);
    p *= dA;
    float r = h * sC[t][n];
    r += __shfl_xor(r, 1);
    r += __shfl_xor(r, 2);
    r += __shfl_xor(r, 4);
    r += __shfl_xor(r, 8);
    if (n == 0) sy[t][dg] = fmaf(uv, Dv, r);
  }

  const size_t abi = (((size_t)b * NCHUNK + c) * 512 + d) * 16 + n;
  Ac[abi] = p;
  Bc[abi] = h;

  __syncthreads();
#pragma unroll
  for (int it = 0; it < 4; ++it) {
    const int t = lt + it * 16;
    y[((size_t)b * L_SEQ + t0 + t) * 512 + d0 + le] = f2bf(sy[t][le]);
  }
}

// ---------------------------------------------------------------------------
// Chunked scan fixup: chunk c>=1: hin = scan of (Ac,Bc) over chunks 0..c-1;
// y_t += C_t . (P_t * hin), P_t running product of dA.
// ---------------------------------------------------------------------------
__global__ __launch_bounds__(256)
void scan_fixup(const float* __restrict__ xo, const float* __restrict__ Alog,
                const float* __restrict__ Ac, const float* __restrict__ Bc,
                u16* __restrict__ y)
{
  const int b = blockIdx.x;
  const int d0 = blockIdx.y * 16;
  const int c = blockIdx.z + 1;        // chunks 1..15
  const int t0 = c * TCHUNK;
  const int tid = threadIdx.x;
  const int n = tid & 15;
  const int dg = tid >> 4;
  const int d = d0 + dg;

  const float Av = -__expf(Alog[d * 16 + n]);

  float hin = 0.f;
  for (int cc = 0; cc < c; ++cc) {
    const size_t abi = (((size_t)b * NCHUNK + cc) * 512 + d) * 16 + n;
    hin = fmaf(Ac[abi], hin, Bc[abi]);
  }

  __shared__ float sdt[TCHUNK][16], sC[TCHUNK][16], sy[TCHUNK][16];
  const int lt = tid >> 4;
  const int le = tid & 15;
#pragma unroll
  for (int it = 0; it < 4; ++it) {
    const int t = lt + it * 16;
    const size_t row = (size_t)b * L_SEQ + t0 + t;
    sdt[t][le] = xo[row * 544 + d0 + le];
    sC [t][le] = xo[row * 544 + 528 + le];
  }
  __syncthreads();

  float p = 1.f;
#pragma unroll 8
  for (int t = 0; t < TCHUNK; ++t) {
    p *= __expf(sdt[t][dg] * Av);
    float r = p * hin * sC[t][n];
    r += __shfl_xor(r, 1);
    r += __shfl_xor(r, 2);
    r += __shfl_xor(r, 4);
    r += __shfl_xor(r, 8);
    if (n == 0) sy[t][dg] = r;
  }
  __syncthreads();
#pragma unroll
  for (int it = 0; it < 4; ++it) {
    const int t = lt + it * 16;
    const size_t idx = ((size_t)b * L_SEQ + t0 + t) * 512 + d0 + le;
    y[idx] = f2bf(bf2f(y[idx]) + sy[t][le]);
  }
}

// ---------------------------------------------------------------------------
// Head (fp32): g = gelu_exact(h_last . p1w^T + p1b); out = g . p2w^T + p2b
// ---------------------------------------------------------------------------
__global__ __launch_bounds__(256)
void head1(const float* __restrict__ h, const float* __restrict__ p1w,
           const float* __restrict__ p1b, float* __restrict__ g)
{
  const int gid = blockIdx.x * 256 + threadIdx.x;  // 8192 = 1024 f x 8 b
  const int f = gid >> 3;
  const int b = gid & 7;
  const float* hr = h + ((size_t)b * L_SEQ + (L_SEQ - 1)) * 256;
  const float* wr = p1w + (size_t)f * 256;
  float acc = 0.f;
#pragma unroll 8
  for (int k = 0; k < 256; k += 4) {
    float4 hv = *reinterpret_cast<const float4*>(hr + k);
    float4 wv = *reinterpret_cast<const float4*>(wr + k);
    acc = fmaf(hv.x, wv.x, acc); acc = fmaf(hv.y, wv.y, acc);
    acc = fmaf(hv.z, wv.z, acc); acc = fmaf(hv.w, wv.w, acc);
  }
  const float xv = acc + p1b[f];
  g[b * 1024 + f] = 0.5f * xv * (1.f + erff(xv * 0.70710678118654752f));
}

__global__ __launch_bounds__(256)
void head2(const float* __restrict__ g, const float* __restrict__ p2w,
           const float* __restrict__ p2b, float* __restrict__ out)
{
  const int b = blockIdx.x;
  const int tid = threadIdx.x;
  float acc = 0.f;
#pragma unroll
  for (int f = tid; f < 1024; f += 256) acc = fmaf(g[b * 1024 + f], p2w[f], acc);
  acc += __shfl_xor(acc, 1);
  acc += __shfl_xor(acc, 2);
  acc += __shfl_xor(acc, 4);
  acc += __shfl_xor(acc, 8);
  acc += __shfl_xor(acc, 16);
  acc += __shfl_xor(acc, 32);
  __shared__ float red[4];
  if ((tid & 63) == 0) red[tid >> 6] = acc;
  __syncthreads();
  if (tid == 0) out[b] = red[0] + red[1] + red[2] + red[3] + p2b[0];
}

// ---------------------------------------------------------------------------
extern "C" void kernel_launch(void* const* d_in, const int* in_sizes, int n_in,
                              void* d_out, int out_size, void* d_ws, size_t ws_size,
                              hipStream_t stream)
{
  const float* x    = (const float*)d_in[0];
  const float* in_w = (const float*)d_in[1];
  const float* in_b = (const float*)d_in[2];
  const float* ipw  = (const float*)d_in[3];
  const float* cw   = (const float*)d_in[4];
  const float* cb   = (const float*)d_in[5];
  const float* xpw  = (const float*)d_in[6];
  const float* dtw  = (const float*)d_in[7];
  const float* dtb  = (const float*)d_in[8];
  const float* Alog = (const float*)d_in[9];
  const float* Dsk  = (const float*)d_in[10];
  const float* opw  = (const float*)d_in[11];
  const float* p1w  = (const float*)d_in[12];
  const float* p1b  = (const float*)d_in[13];
  const float* p2w  = (const float*)d_in[14];
  const float* p2b  = (const float*)d_in[15];

  float* ws = (float*)d_ws;
  float* h    = ws;                       // 8192*256 f32        (2,097,152 fw)
  u16*   xz16 = (u16*)(ws + 2097152);     // 8192*1024 bf16      (4,194,304 fw)
  u16*   xc16 = (u16*)(ws + 6291456);     // 8192*512 bf16       (2,097,152 fw)
  float* xo   = ws + 8388608;             // 8192*544 f32        (4,456,448 fw)
  u16*   wc16 = (u16*)(ws + 12845056);    // 2*544*512 bf16      (  278,528 fw)
  float* g    = ws + 13123584;            // 8*1024 f32
  u16*   y16  = xc16;                     // alias: scan stages chunk before store
  // Ac/Bc alias h (dead between in_proj read and out_proj write; scan inside)
  float* Ac   = h;
  float* Bc   = h + 1048576;
  // total ~52.5 MB

  // combined x_proj/dt_proj weights (both layers)
  wprep<<<dim3(544, 2), 512, 0, stream>>>(dtw, xpw, wc16);

  // embed: h = x @ in_w^T + in_b  (M=8192,N=256,K=32) fp32
  sgemm_nt<32, 64, 16, 4, 4><<<dim3(M_ROWS / 32, 4), 128, 0, stream>>>(
      x, 32, in_w, 32, in_b, h, 256, 256, 32);

  for (int layer = 0; layer < 2; ++layer) {
    const float* ipw_l = ipw + (size_t)layer * 1024 * 256;
    const float* cw_l  = cw  + (size_t)layer * 512 * 4;
    const float* cb_l  = cb  + (size_t)layer * 512;
    const float* dtb_l = dtb + (size_t)layer * 512;
    const float* Al_l  = Alog + (size_t)layer * 512 * 16;
    const float* Dsk_l = Dsk + (size_t)layer * 512;
    const float* opw_l = opw + (size_t)layer * 256 * 512;
    const u16*   wc_l  = wc16 + (size_t)layer * 544 * 512;

    // xz = h @ ipw^T  (N=1024,K=256) -> bf16
    gemm_bf<128, 128, 2, 2, 0, 0, 0, 1><<<dim3(M_ROWS / 128, 8), 256, 0, stream>>>(
        h, 256, nullptr, 0, ipw_l, 256, nullptr, xz16, 1024, 1024, 256);

    // xc = silu(causal_dwconv(xz[:, :512]) + cb) -> bf16
    conv_silu<<<dim3(8, 32), 512, 0, stream>>>(xz16, cw_l, cb_l, xc16);

    // xo = [softplus(xc@Wdt^T + dtb) | B | C]  (N=544,K=512) -> f32
    gemm_bf<64, 128, 2, 2, 1, 1, 2, 0><<<dim3(M_ROWS / 64, 5), 256, 0, stream>>>(
        xc16, 512, nullptr, 0, wc_l, 512, dtb_l, xo, 544, 544, 512);

    // chunked selective scan -> y16 (in place over xc16), includes +u*D
    scan_part1<<<dim3(8, 32, NCHUNK), 256, 0, stream>>>(
        xo, xc16, Al_l, Dsk_l, y16, Ac, Bc);
    scan_fixup<<<dim3(8, 32, NCHUNK - 1), 256, 0, stream>>>(
        xo, Al_l, Ac, Bc, y16);

    // h = (y * silu(z)) @ opw^T  (N=256,K=512) -> f32; z = xz[:,512:]
    gemm_bf<64, 128, 2, 2, 2, 0, 0, 0><<<dim3(M_ROWS / 64, 2), 256, 0, stream>>>(
        y16, 512, xz16 + 512, 1024, opw_l, 512, nullptr, h, 256, 256, 512);
  }

  head1<<<32, 256, 0, stream>>>(h, p1w, p1b, g);
  head2<<<8, 256, 0, stream>>>(g, p2w, p2b, (float*)d_out);
}

// Round 5
// 410.998 us; speedup vs baseline: 2.3220x; 1.3425x over previous
//
#include <hip/hip_runtime.h>
#include <math.h>

// ---------------------------------------------------------------------------
// Mamba forward. Round 5: register-state selective scan (h[16] per thread, no
// shuffles, no per-t LDS transpose). Round-4 scan was DS-pipe bound (8 DS ops
// x 1.05M wave-iters ~= 77us, matching measurement). bf16 MFMA GEMMs kept.
// Shapes: B=8 L=1024 ENC=32 DM=256 DI=512 DS=16 DC=4 DTR=16 LAYERS=2 DFF=1024
// ---------------------------------------------------------------------------

static constexpr int L_SEQ = 1024;
static constexpr int M_ROWS = 8 * 1024;   // B*L
static constexpr int NCHUNK = 32;
static constexpr int TCHUNK = 32;         // L_SEQ / NCHUNK

typedef unsigned short u16;
typedef unsigned short u16x8 __attribute__((ext_vector_type(8)));
typedef short bf16x8 __attribute__((ext_vector_type(8)));   // MFMA operand type
typedef float f32x4 __attribute__((ext_vector_type(4)));

__device__ __forceinline__ float silu_f(float x) { return x / (1.f + __expf(-x)); }
__device__ __forceinline__ float softplus_f(float x) {
  return (x > 20.f) ? x : log1pf(__expf(x));
}
__device__ __forceinline__ u16 f2bf(float f) {          // RNE fp32->bf16
  unsigned u = __builtin_bit_cast(unsigned, f);
  u += 0x7FFFu + ((u >> 16) & 1u);
  return (u16)(u >> 16);
}
__device__ __forceinline__ float bf2f(u16 v) {
  return __builtin_bit_cast(float, (unsigned)v << 16);
}
__device__ __forceinline__ u16x8 cvt8(const float* p) { // 8 fp32 -> 8 bf16
  float4 a = *reinterpret_cast<const float4*>(p);
  float4 b = *reinterpret_cast<const float4*>(p + 4);
  u16x8 v;
  v[0] = f2bf(a.x); v[1] = f2bf(a.y); v[2] = f2bf(a.z); v[3] = f2bf(a.w);
  v[4] = f2bf(b.x); v[5] = f2bf(b.y); v[6] = f2bf(b.z); v[7] = f2bf(b.w);
  return v;
}

// ---------------------------------------------------------------------------
// bf16 MFMA GEMM:  C[m,n] = epi( sum_k A[m,k] * W[n,k] ), fp32 accumulate.
// 256 threads = 4 waves (WR x WC). MFMA 16x16x32_bf16, BK=32.
// AMODE: 0 A fp32 (cast); 1 A bf16; 2 A bf16 * silu(Z bf16)
// WBF:   0 W fp32 (cast); 1 W bf16
// EPI:   0 none; 1 +bias; 2 combo: n<512 -> softplus(c+bias[n]), else raw
// OUTBF: output bf16 else fp32
// ---------------------------------------------------------------------------
template<int BM,int BN,int WR,int WC,int AMODE,int WBF,int EPI,int OUTBF>
__global__ __launch_bounds__(256)
void gemm_bf(const void* __restrict__ Ap, int lda,
             const void* __restrict__ Zp, int ldz,
             const void* __restrict__ Wp, int ldw,
             const float* __restrict__ bias,
             void* __restrict__ Cp, int ldc,
             int N, int K)
{
  constexpr int SK = 40;                  // LDS stride (bf16): 32 + 8 pad
  constexpr int TI = BM / WR / 16;
  constexpr int TJ = BN / WC / 16;

  __shared__ u16 As[BM * SK];
  __shared__ u16 Ws[BN * SK];

  const int tid = threadIdx.x;
  const int bm = blockIdx.x * BM;
  const int bn = blockIdx.y * BN;
  const int lane = tid & 63;
  const int wv = tid >> 6;
  const int wy = wv / WC, wx = wv % WC;
  const int rb = wy * (BM / WR);
  const int cb = wx * (BN / WC);
  const int lr = lane & 15, lq = lane >> 4;

  f32x4 acc[TI][TJ];
#pragma unroll
  for (int i = 0; i < TI; ++i)
#pragma unroll
    for (int j = 0; j < TJ; ++j) acc[i][j] = (f32x4){0.f, 0.f, 0.f, 0.f};

  for (int k0 = 0; k0 < K; k0 += 32) {
#pragma unroll
    for (int c = tid; c < BM * 4; c += 256) {
      const int r = c >> 2, kh = (c & 3) * 8;
      u16x8 v;
      if (AMODE == 0) {
        v = cvt8((const float*)Ap + (size_t)(bm + r) * lda + k0 + kh);
      } else {
        v = *reinterpret_cast<const u16x8*>(
              (const u16*)Ap + (size_t)(bm + r) * lda + k0 + kh);
        if (AMODE == 2) {
          u16x8 z = *reinterpret_cast<const u16x8*>(
                      (const u16*)Zp + (size_t)(bm + r) * ldz + k0 + kh);
#pragma unroll
          for (int j = 0; j < 8; ++j)
            v[j] = f2bf(bf2f(v[j]) * silu_f(bf2f(z[j])));
        }
      }
      *reinterpret_cast<u16x8*>(&As[r * SK + kh]) = v;
    }
#pragma unroll
    for (int c = tid; c < BN * 4; c += 256) {
      const int r = c >> 2, kh = (c & 3) * 8;
      const int n = bn + r;
      u16x8 v = (u16x8){0,0,0,0,0,0,0,0};
      if (n < N) {
        if (WBF) v = *reinterpret_cast<const u16x8*>(
                       (const u16*)Wp + (size_t)n * ldw + k0 + kh);
        else     v = cvt8((const float*)Wp + (size_t)n * ldw + k0 + kh);
      }
      *reinterpret_cast<u16x8*>(&Ws[r * SK + kh]) = v;
    }
    __syncthreads();

    bf16x8 af[TI], bf[TJ];
#pragma unroll
    for (int i = 0; i < TI; ++i)
      af[i] = *reinterpret_cast<const bf16x8*>(&As[(rb + i * 16 + lr) * SK + lq * 8]);
#pragma unroll
    for (int j = 0; j < TJ; ++j)
      bf[j] = *reinterpret_cast<const bf16x8*>(&Ws[(cb + j * 16 + lr) * SK + lq * 8]);
#pragma unroll
    for (int i = 0; i < TI; ++i)
#pragma unroll
      for (int j = 0; j < TJ; ++j)
        acc[i][j] = __builtin_amdgcn_mfma_f32_16x16x32_bf16(af[i], bf[j], acc[i][j], 0, 0, 0);
    __syncthreads();
  }

#pragma unroll
  for (int i = 0; i < TI; ++i) {
#pragma unroll
    for (int j = 0; j < TJ; ++j) {
      const int col = bn + cb + j * 16 + lr;
      if (col >= N) continue;
#pragma unroll
      for (int r = 0; r < 4; ++r) {
        const int row = bm + rb + i * 16 + lq * 4 + r;
        float c = acc[i][j][r];
        if (EPI == 1) c += bias[col];
        if (EPI == 2) { if (col < 512) c = softplus_f(c + bias[col]); }
        if (OUTBF) ((u16*)Cp)[(size_t)row * ldc + col] = f2bf(c);
        else       ((float*)Cp)[(size_t)row * ldc + col] = c;
      }
    }
  }
}

// ---------------------------------------------------------------------------
// fp32 SGEMM (embed only: M=8192, N=256, K=32)
// ---------------------------------------------------------------------------
template<int BM,int BN,int BK,int TM,int TN>
__global__ __launch_bounds__((BM/TM)*(BN/TN))
void sgemm_nt(const float* __restrict__ A, int lda,
              const float* __restrict__ W, int ldw,
              const float* __restrict__ bias,
              float* __restrict__ C, int ldc, int N, int K)
{
  constexpr int TX = BN / TN;
  constexpr int TY = BM / TM;
  constexpr int NT = TX * TY;
  constexpr int KQ = BK / 4;
  constexpr int RPP = NT / KQ;

  __shared__ float As[BK][BM + 4];
  __shared__ float Bs[BK][BN + 4];

  const int tid = threadIdx.x;
  const int tx = tid % TX, ty = tid / TX;
  const int bm = blockIdx.x * BM;
  const int bn = blockIdx.y * BN;

  float acc[TM][TN];
#pragma unroll
  for (int i = 0; i < TM; ++i)
#pragma unroll
    for (int j = 0; j < TN; ++j) acc[i][j] = 0.f;

  const int lr = tid / KQ;
  const int lk = (tid % KQ) * 4;

  for (int k0 = 0; k0 < K; k0 += BK) {
#pragma unroll
    for (int r = lr; r < BM; r += RPP) {
      float4 v = *reinterpret_cast<const float4*>(A + (size_t)(bm + r) * lda + k0 + lk);
      As[lk + 0][r] = v.x; As[lk + 1][r] = v.y;
      As[lk + 2][r] = v.z; As[lk + 3][r] = v.w;
    }
#pragma unroll
    for (int r = lr; r < BN; r += RPP) {
      float4 v = *reinterpret_cast<const float4*>(W + (size_t)(bn + r) * ldw + k0 + lk);
      Bs[lk + 0][r] = v.x; Bs[lk + 1][r] = v.y;
      Bs[lk + 2][r] = v.z; Bs[lk + 3][r] = v.w;
    }
    __syncthreads();
#pragma unroll
    for (int kk = 0; kk < BK; ++kk) {
      float a[TM], b[TN];
#pragma unroll
      for (int i = 0; i < TM; ++i) a[i] = As[kk][ty * TM + i];
#pragma unroll
      for (int j = 0; j < TN; ++j) b[j] = Bs[kk][tx * TN + j];
#pragma unroll
      for (int i = 0; i < TM; ++i)
#pragma unroll
        for (int j = 0; j < TN; ++j) acc[i][j] = fmaf(a[i], b[j], acc[i][j]);
    }
    __syncthreads();
  }
#pragma unroll
  for (int i = 0; i < TM; ++i) {
    const int m = bm + ty * TM + i;
#pragma unroll
    for (int j = 0; j < TN; j += 4) {
      const int n = bn + tx * TN + j;
      float4 v;
      v.x = acc[i][j + 0] + bias[n + 0];
      v.y = acc[i][j + 1] + bias[n + 1];
      v.z = acc[i][j + 2] + bias[n + 2];
      v.w = acc[i][j + 3] + bias[n + 3];
      *reinterpret_cast<float4*>(C + (size_t)m * ldc + n) = v;
    }
  }
}

// ---------------------------------------------------------------------------
// W_combo precompute: rows 0..511 = dtw(512x16) . xpw[0:16,:] (dt folded),
// rows 512..527 = xpw[16:32,:] (B), rows 528..543 = xpw[32:48,:] (C). bf16 out.
// ---------------------------------------------------------------------------
__global__ __launch_bounds__(512)
void wprep(const float* __restrict__ dtw, const float* __restrict__ xpw,
           u16* __restrict__ wc)
{
  const int layer = blockIdx.y;
  const int n = blockIdx.x;      // 0..543
  const int k = threadIdx.x;     // 0..511
  const float* xp = xpw + (size_t)layer * 48 * 512;
  float v;
  if (n < 512) {
    const float* dw = dtw + (size_t)layer * 512 * 16 + n * 16;
    v = 0.f;
#pragma unroll
    for (int r = 0; r < 16; ++r) v = fmaf(dw[r], xp[r * 512 + k], v);
  } else {
    v = xp[(16 + (n - 512)) * 512 + k];
  }
  wc[((size_t)layer * 544 + n) * 512 + k] = f2bf(v);
}

// ---------------------------------------------------------------------------
// Causal depthwise conv (width 4) + bias + silu. xz bf16 (b,l,1024)[:,:512] -> xc bf16
// ---------------------------------------------------------------------------
__global__ __launch_bounds__(512)
void conv_silu(const u16* __restrict__ xz, const float* __restrict__ cw,
               const float* __restrict__ cb, u16* __restrict__ xc)
{
  const int b = blockIdx.x;          // 8
  const int l0 = blockIdx.y * 32;    // 32 chunks of 32
  const int d = threadIdx.x;         // 512

  const float w0 = cw[d * 4 + 0], w1 = cw[d * 4 + 1];
  const float w2 = cw[d * 4 + 2], w3 = cw[d * 4 + 3];
  const float bias = cb[d];

  const size_t base = ((size_t)b * L_SEQ) * 1024 + d;
  float xm3 = (l0 >= 3) ? bf2f(xz[base + (size_t)(l0 - 3) * 1024]) : 0.f;
  float xm2 = (l0 >= 2) ? bf2f(xz[base + (size_t)(l0 - 2) * 1024]) : 0.f;
  float xm1 = (l0 >= 1) ? bf2f(xz[base + (size_t)(l0 - 1) * 1024]) : 0.f;

#pragma unroll 4
  for (int i = 0; i < 32; ++i) {
    const int l = l0 + i;
    const float x0 = bf2f(xz[base + (size_t)l * 1024]);
    const float v = bias + w0 * xm3 + w1 * xm2 + w2 * xm1 + w3 * x0;
    xc[((size_t)b * L_SEQ + l) * 512 + d] = f2bf(silu_f(v));
    xm3 = xm2; xm2 = xm1; xm1 = x0;
  }
}

// ---------------------------------------------------------------------------
// Scan pass A: per-chunk aggregates only. One thread per d; h[16]/p[16] in
// registers; B chunk staged in LDS, read back as b128 broadcasts.
// Ac[(b,c,d,n)] = prod_t dA;  Bc = local final h (h0=0).
// ---------------------------------------------------------------------------
__global__ __launch_bounds__(256)
void scan_passA(const float* __restrict__ xo, const u16* __restrict__ u,
                const float* __restrict__ Alog,
                float* __restrict__ Ac, float* __restrict__ Bc)
{
  const int b = blockIdx.x;
  const int d = blockIdx.y * 256 + threadIdx.x;
  const int c = blockIdx.z;
  const int t0 = c * TCHUNK;

  __shared__ float sB[TCHUNK][16];
#pragma unroll
  for (int r = 0; r < TCHUNK * 16; r += 256) {
    const int e = threadIdx.x + r;
    const int t = e >> 4, n = e & 15;
    sB[t][n] = xo[((size_t)b * L_SEQ + t0 + t) * 544 + 512 + n];
  }
  __syncthreads();

  float A[16], h[16], p[16];
  const float* al = Alog + d * 16;
#pragma unroll
  for (int n = 0; n < 16; ++n) { A[n] = -__expf(al[n]); h[n] = 0.f; p[n] = 1.f; }

#pragma unroll 2
  for (int t = 0; t < TCHUNK; ++t) {
    const size_t row = (size_t)b * L_SEQ + t0 + t;
    const float dtv = xo[row * 544 + d];
    const float uv  = bf2f(u[row * 512 + d]);
    const float cf  = dtv * uv;
    const f32x4* Bq = reinterpret_cast<const f32x4*>(&sB[t][0]);
#pragma unroll
    for (int q = 0; q < 4; ++q) {
      const f32x4 Bv = Bq[q];
#pragma unroll
      for (int k = 0; k < 4; ++k) {
        const int n = q * 4 + k;
        const float dA = __expf(dtv * A[n]);
        p[n] *= dA;
        h[n] = fmaf(dA, h[n], cf * Bv[k]);
      }
    }
  }

  float* ac = Ac + (((size_t)b * NCHUNK + c) * 512 + d) * 16;
  float* bc = Bc + (((size_t)b * NCHUNK + c) * 512 + d) * 16;
#pragma unroll
  for (int q = 0; q < 4; ++q) {
    f32x4 va, vb;
#pragma unroll
    for (int k = 0; k < 4; ++k) { va[k] = p[q * 4 + k]; vb[k] = h[q * 4 + k]; }
    reinterpret_cast<f32x4*>(ac)[q] = va;
    reinterpret_cast<f32x4*>(bc)[q] = vb;
  }
}

// ---------------------------------------------------------------------------
// Scan pass B: full scan per chunk, seeded with h_in derived from Ac/Bc of
// preceding chunks (register prologue). Writes y bf16 (aliases u: read-before-
// write per row). y includes +u*D.
// ---------------------------------------------------------------------------
__global__ __launch_bounds__(256)
void scan_passB(const float* __restrict__ xo, const u16* __restrict__ u,
                const float* __restrict__ Alog, const float* __restrict__ Dsk,
                const float* __restrict__ Ac, const float* __restrict__ Bc,
                u16* __restrict__ y)
{
  const int b = blockIdx.x;
  const int d = blockIdx.y * 256 + threadIdx.x;
  const int c = blockIdx.z;
  const int t0 = c * TCHUNK;

  __shared__ float sB[TCHUNK][16], sC[TCHUNK][16];
#pragma unroll
  for (int r = 0; r < TCHUNK * 16; r += 256) {
    const int e = threadIdx.x + r;
    const int t = e >> 4, n = e & 15;
    const size_t row = (size_t)b * L_SEQ + t0 + t;
    sB[t][n] = xo[row * 544 + 512 + n];
    sC[t][n] = xo[row * 544 + 528 + n];
  }
  __syncthreads();

  float A[16], h[16];
  const float* al = Alog + d * 16;
#pragma unroll
  for (int n = 0; n < 16; ++n) { A[n] = -__expf(al[n]); h[n] = 0.f; }

  // h_in = chunk-level scan over aggregates of chunks 0..c-1
  for (int cc = 0; cc < c; ++cc) {
    const float* ac = Ac + (((size_t)b * NCHUNK + cc) * 512 + d) * 16;
    const float* bc = Bc + (((size_t)b * NCHUNK + cc) * 512 + d) * 16;
#pragma unroll
    for (int q = 0; q < 4; ++q) {
      const f32x4 va = reinterpret_cast<const f32x4*>(ac)[q];
      const f32x4 vb = reinterpret_cast<const f32x4*>(bc)[q];
#pragma unroll
      for (int k = 0; k < 4; ++k) {
        const int n = q * 4 + k;
        h[n] = fmaf(va[k], h[n], vb[k]);
      }
    }
  }

  const float Dv = Dsk[d];

#pragma unroll 2
  for (int t = 0; t < TCHUNK; ++t) {
    const size_t row = (size_t)b * L_SEQ + t0 + t;
    const float dtv = xo[row * 544 + d];
    const float uv  = bf2f(u[row * 512 + d]);
    const float cf  = dtv * uv;
    const f32x4* Bq = reinterpret_cast<const f32x4*>(&sB[t][0]);
    const f32x4* Cq = reinterpret_cast<const f32x4*>(&sC[t][0]);
    float s0 = 0.f, s1 = 0.f, s2 = 0.f, s3 = 0.f;
#pragma unroll
    for (int q = 0; q < 4; ++q) {
      const f32x4 Bv = Bq[q];
      const f32x4 Cv = Cq[q];
#pragma unroll
      for (int k = 0; k < 4; ++k) {
        const int n = q * 4 + k;
        const float dA = __expf(dtv * A[n]);
        h[n] = fmaf(dA, h[n], cf * Bv[k]);
      }
      s0 = fmaf(h[q * 4 + 0], Cv[0], s0);
      s1 = fmaf(h[q * 4 + 1], Cv[1], s1);
      s2 = fmaf(h[q * 4 + 2], Cv[2], s2);
      s3 = fmaf(h[q * 4 + 3], Cv[3], s3);
    }
    y[row * 512 + d] = f2bf(fmaf(uv, Dv, (s0 + s1) + (s2 + s3)));
  }
}

// ---------------------------------------------------------------------------
// Head (fp32): g = gelu_exact(h_last . p1w^T + p1b); out = g . p2w^T + p2b
// ---------------------------------------------------------------------------
__global__ __launch_bounds__(256)
void head1(const float* __restrict__ h, const float* __restrict__ p1w,
           const float* __restrict__ p1b, float* __restrict__ g)
{
  const int gid = blockIdx.x * 256 + threadIdx.x;  // 8192 = 1024 f x 8 b
  const int f = gid >> 3;
  const int b = gid & 7;
  const float* hr = h + ((size_t)b * L_SEQ + (L_SEQ - 1)) * 256;
  const float* wr = p1w + (size_t)f * 256;
  float acc = 0.f;
#pragma unroll 8
  for (int k = 0; k < 256; k += 4) {
    float4 hv = *reinterpret_cast<const float4*>(hr + k);
    float4 wv = *reinterpret_cast<const float4*>(wr + k);
    acc = fmaf(hv.x, wv.x, acc); acc = fmaf(hv.y, wv.y, acc);
    acc = fmaf(hv.z, wv.z, acc); acc = fmaf(hv.w, wv.w, acc);
  }
  const float xv = acc + p1b[f];
  g[b * 1024 + f] = 0.5f * xv * (1.f + erff(xv * 0.70710678118654752f));
}

__global__ __launch_bounds__(256)
void head2(const float* __restrict__ g, const float* __restrict__ p2w,
           const float* __restrict__ p2b, float* __restrict__ out)
{
  const int b = blockIdx.x;
  const int tid = threadIdx.x;
  float acc = 0.f;
#pragma unroll
  for (int f = tid; f < 1024; f += 256) acc = fmaf(g[b * 1024 + f], p2w[f], acc);
  acc += __shfl_xor(acc, 1);
  acc += __shfl_xor(acc, 2);
  acc += __shfl_xor(acc, 4);
  acc += __shfl_xor(acc, 8);
  acc += __shfl_xor(acc, 16);
  acc += __shfl_xor(acc, 32);
  __shared__ float red[4];
  if ((tid & 63) == 0) red[tid >> 6] = acc;
  __syncthreads();
  if (tid == 0) out[b] = red[0] + red[1] + red[2] + red[3] + p2b[0];
}

// ---------------------------------------------------------------------------
extern "C" void kernel_launch(void* const* d_in, const int* in_sizes, int n_in,
                              void* d_out, int out_size, void* d_ws, size_t ws_size,
                              hipStream_t stream)
{
  const float* x    = (const float*)d_in[0];
  const float* in_w = (const float*)d_in[1];
  const float* in_b = (const float*)d_in[2];
  const float* ipw  = (const float*)d_in[3];
  const float* cw   = (const float*)d_in[4];
  const float* cb   = (const float*)d_in[5];
  const float* xpw  = (const float*)d_in[6];
  const float* dtw  = (const float*)d_in[7];
  const float* dtb  = (const float*)d_in[8];
  const float* Alog = (const float*)d_in[9];
  const float* Dsk  = (const float*)d_in[10];
  const float* opw  = (const float*)d_in[11];
  const float* p1w  = (const float*)d_in[12];
  const float* p1b  = (const float*)d_in[13];
  const float* p2w  = (const float*)d_in[14];
  const float* p2b  = (const float*)d_in[15];

  float* ws = (float*)d_ws;
  float* h    = ws;                       // 8192*256 f32        (2,097,152 fw)
  u16*   xz16 = (u16*)(ws + 2097152);     // 8192*1024 bf16      (4,194,304 fw)
  u16*   xc16 = (u16*)(ws + 6291456);     // 8192*512 bf16       (2,097,152 fw)
  float* xo   = ws + 8388608;             // 8192*544 f32        (4,456,448 fw)
  u16*   wc16 = (u16*)(ws + 12845056);    // 2*544*512 bf16      (  278,528 fw)
  float* g    = ws + 13123584;            // 8*1024 f32          (pad to 8,192)
  float* Bc   = ws + 13131776;            // 8*32*512*16 f32     (2,097,152 fw)
  u16*   y16  = xc16;                     // alias: read-before-write per row
  // Ac aliases h exactly (8*32*512*16 = 2,097,152 = h size); h is dead between
  // the in_proj GEMM (reads h) and the out_proj GEMM (rewrites h).
  float* Ac   = h;
  // total ~60.9 MB

  // combined x_proj/dt_proj weights (both layers)
  wprep<<<dim3(544, 2), 512, 0, stream>>>(dtw, xpw, wc16);

  // embed: h = x @ in_w^T + in_b  (M=8192,N=256,K=32) fp32
  sgemm_nt<32, 64, 16, 4, 4><<<dim3(M_ROWS / 32, 4), 128, 0, stream>>>(
      x, 32, in_w, 32, in_b, h, 256, 256, 32);

  for (int layer = 0; layer < 2; ++layer) {
    const float* ipw_l = ipw + (size_t)layer * 1024 * 256;
    const float* cw_l  = cw  + (size_t)layer * 512 * 4;
    const float* cb_l  = cb  + (size_t)layer * 512;
    const float* dtb_l = dtb + (size_t)layer * 512;
    const float* Al_l  = Alog + (size_t)layer * 512 * 16;
    const float* Dsk_l = Dsk + (size_t)layer * 512;
    const float* opw_l = opw + (size_t)layer * 256 * 512;
    const u16*   wc_l  = wc16 + (size_t)layer * 544 * 512;

    // xz = h @ ipw^T  (N=1024,K=256) -> bf16
    gemm_bf<128, 128, 2, 2, 0, 0, 0, 1><<<dim3(M_ROWS / 128, 8), 256, 0, stream>>>(
        h, 256, nullptr, 0, ipw_l, 256, nullptr, xz16, 1024, 1024, 256);

    // xc = silu(causal_dwconv(xz[:, :512]) + cb) -> bf16
    conv_silu<<<dim3(8, 32), 512, 0, stream>>>(xz16, cw_l, cb_l, xc16);

    // xo = [softplus(xc@Wdt^T + dtb) | B | C]  (N=544,K=512) -> f32
    gemm_bf<64, 128, 2, 2, 1, 1, 2, 0><<<dim3(M_ROWS / 64, 5), 256, 0, stream>>>(
        xc16, 512, nullptr, 0, wc_l, 512, dtb_l, xo, 544, 544, 512);

    // selective scan: passA (chunk aggregates) + passB (seeded full scan -> y)
    scan_passA<<<dim3(8, 2, NCHUNK), 256, 0, stream>>>(
        xo, xc16, Al_l, Ac, Bc);
    scan_passB<<<dim3(8, 2, NCHUNK), 256, 0, stream>>>(
        xo, xc16, Al_l, Dsk_l, Ac, Bc, y16);

    // h = (y * silu(z)) @ opw^T  (N=256,K=512) -> f32; z = xz[:,512:]
    gemm_bf<64, 128, 2, 2, 2, 0, 0, 0><<<dim3(M_ROWS / 64, 2), 256, 0, stream>>>(
        y16, 512, xz16 + 512, 1024, opw_l, 512, nullptr, h, 256, 256, 512);
  }

  head1<<<32, 256, 0, stream>>>(h, p1w, p1b, g);
  head2<<<8, 256, 0, stream>>>(g, p2w, p2b, (float*)d_out);
}

// Round 6
// 385.628 us; speedup vs baseline: 2.4748x; 1.0658x over previous
//
#include <hip/hip_runtime.h>
#include <math.h>

// ---------------------------------------------------------------------------
// Mamba forward. Round 6:
//  - scan_mid kernel: exclusive-prefix chunk states (kills passB's O(NCHUNK^2)
//    Ac/Bc re-read, ~260 MB -> 24 MB)
//  - all-bf16 GEMM operands + __builtin_amdgcn_global_load_lds width-16
//    staging (m93->m97 ladder step), unpadded lane-contiguous LDS layout
//  - y*silu(z) gate fused into scan passB; h stored bf16; embed via MFMA
// Shapes: B=8 L=1024 ENC=32 DM=256 DI=512 DS=16 DC=4 DTR=16 LAYERS=2 DFF=1024
// ---------------------------------------------------------------------------

static constexpr int L_SEQ = 1024;
static constexpr int M_ROWS = 8 * 1024;   // B*L
static constexpr int NCHUNK = 32;
static constexpr int TCHUNK = 32;         // L_SEQ / NCHUNK

typedef unsigned short u16;
typedef unsigned short u16x8 __attribute__((ext_vector_type(8)));
typedef unsigned short u16x4 __attribute__((ext_vector_type(4)));
typedef short bf16x8 __attribute__((ext_vector_type(8)));   // MFMA operand type
typedef float f32x4 __attribute__((ext_vector_type(4)));

__device__ __forceinline__ float silu_f(float x) { return x / (1.f + __expf(-x)); }
__device__ __forceinline__ float softplus_f(float x) {
  return (x > 20.f) ? x : log1pf(__expf(x));
}
__device__ __forceinline__ u16 f2bf(float f) {          // RNE fp32->bf16
  unsigned u = __builtin_bit_cast(unsigned, f);
  u += 0x7FFFu + ((u >> 16) & 1u);
  return (u16)(u >> 16);
}
__device__ __forceinline__ float bf2f(u16 v) {
  return __builtin_bit_cast(float, (unsigned)v << 16);
}

// async global->LDS, 16 B per lane; LDS dest = uniform base + lane*16
__device__ __forceinline__ void gll16(const u16* g, u16* l) {
  __builtin_amdgcn_global_load_lds(
      (const __attribute__((address_space(1))) void*)g,
      (__attribute__((address_space(3))) void*)l, 16, 0, 0);
}

// ---------------------------------------------------------------------------
// bf16 MFMA GEMM, async-staged:  C[m,n] = epi( sum_k A[m,k] * W[n,k] ).
// All operands bf16 row-major (A: MxK lda, W: NxK ldw). 256 thr = 4 waves,
// each wave computes (BM/2)x(BN/2). MFMA 16x16x32_bf16, BK=32.
// LDS layout: slot(lq,row) = lq*BM + row holds A[row][k0+lq*8 .. +8) (16 B).
// Staged via global_load_lds in 1 KB windows (64 rows x one lq), lane=row.
// Frag read: lane reads slot(lane>>4, rb+i*16+(lane&15)) as b128 - contiguous
// per 16-lane group -> conflict-free.
// EPI: 0 none; 1 +bias; 2 combo (col<512 -> softplus(c+bias[col]), else raw)
// OUTBF: 1 -> bf16 store, 0 -> fp32 store.
// BM, BN multiples of 64; M % BM == 0; W must have >= gridDim.y*BN valid rows.
// ---------------------------------------------------------------------------
template<int BM,int BN,int EPI,int OUTBF>
__global__ __launch_bounds__(256)
void gemm_async(const u16* __restrict__ A, int lda,
                const u16* __restrict__ W, int ldw,
                const float* __restrict__ bias,
                void* __restrict__ Cp, int ldc,
                int N, int K)
{
  constexpr int RWA = BM / 64, RWB = BN / 64;
  constexpr int NWA = 4 * RWA, NWB = 4 * RWB;
  constexpr int NWT = NWA + NWB;
  constexpr int TI = BM / 2 / 16;
  constexpr int TJ = BN / 2 / 16;

  __shared__ u16 As[BM * 32];
  __shared__ u16 Ws[BN * 32];

  const int tid = threadIdx.x;
  const int lane = tid & 63;
  const int wv = tid >> 6;
  const int wy = wv >> 1, wx = wv & 1;
  const int rb = wy * (BM / 2);
  const int cb = wx * (BN / 2);
  const int lr = lane & 15, lq = lane >> 4;
  const int bm = blockIdx.x * BM;
  const int bn = blockIdx.y * BN;

  f32x4 acc[TI][TJ];
#pragma unroll
  for (int i = 0; i < TI; ++i)
#pragma unroll
    for (int j = 0; j < TJ; ++j) acc[i][j] = (f32x4){0.f, 0.f, 0.f, 0.f};

  for (int k0 = 0; k0 < K; k0 += 32) {
#pragma unroll
    for (int w = wv; w < NWT; w += 4) {
      if (w < NWA) {
        const int lqw = w / RWA, rh = w % RWA;
        const u16* g = A + (size_t)(bm + rh * 64 + lane) * lda + k0 + lqw * 8;
        gll16(g, &As[(lqw * BM + rh * 64) * 8]);
      } else {
        const int w2 = w - NWA;
        const int lqw = w2 / RWB, rh = w2 % RWB;
        const u16* g = W + (size_t)(bn + rh * 64 + lane) * ldw + k0 + lqw * 8;
        gll16(g, &Ws[(lqw * BN + rh * 64) * 8]);
      }
    }
    __syncthreads();

    bf16x8 af[TI], bf[TJ];
#pragma unroll
    for (int i = 0; i < TI; ++i)
      af[i] = *reinterpret_cast<const bf16x8*>(&As[(lq * BM + rb + i * 16 + lr) * 8]);
#pragma unroll
    for (int j = 0; j < TJ; ++j)
      bf[j] = *reinterpret_cast<const bf16x8*>(&Ws[(lq * BN + cb + j * 16 + lr) * 8]);
#pragma unroll
    for (int i = 0; i < TI; ++i)
#pragma unroll
      for (int j = 0; j < TJ; ++j)
        acc[i][j] = __builtin_amdgcn_mfma_f32_16x16x32_bf16(af[i], bf[j], acc[i][j], 0, 0, 0);
    __syncthreads();
  }

#pragma unroll
  for (int i = 0; i < TI; ++i) {
#pragma unroll
    for (int j = 0; j < TJ; ++j) {
      const int col = bn + cb + j * 16 + lr;
      if (col >= N) continue;
#pragma unroll
      for (int r = 0; r < 4; ++r) {
        const int row = bm + rb + i * 16 + lq * 4 + r;
        float c = acc[i][j][r];
        if (EPI == 1) c += bias[col];
        if (EPI == 2) { if (col < 512) c = softplus_f(c + bias[col]); }
        if (OUTBF) ((u16*)Cp)[(size_t)row * ldc + col] = f2bf(c);
        else       ((float*)Cp)[(size_t)row * ldc + col] = c;
      }
    }
  }
}

// ---------------------------------------------------------------------------
// fp32 -> bf16 cast (4 elems/thread)
// ---------------------------------------------------------------------------
__global__ __launch_bounds__(256)
void cast_f2b(const float* __restrict__ src, u16* __restrict__ dst, int n)
{
  const int i = (blockIdx.x * 256 + threadIdx.x) * 4;
  if (i >= n) return;
  float4 v = *reinterpret_cast<const float4*>(src + i);
  u16x4 o;
  o[0] = f2bf(v.x); o[1] = f2bf(v.y); o[2] = f2bf(v.z); o[3] = f2bf(v.w);
  *reinterpret_cast<u16x4*>(dst + i) = o;
}

// ---------------------------------------------------------------------------
// W_combo: rows 0..511 = dtw(512x16).xpw[0:16,:] (dt proj folded), 512..527 =
// xpw[16:32,:] (B), 528..543 = xpw[32:48,:] (C), 544..639 = 0 (pad). bf16.
// ---------------------------------------------------------------------------
__global__ __launch_bounds__(512)
void wprep(const float* __restrict__ dtw, const float* __restrict__ xpw,
           u16* __restrict__ wc)
{
  const int layer = blockIdx.y;
  const int n = blockIdx.x;      // 0..639
  const int k = threadIdx.x;     // 0..511
  const float* xp = xpw + (size_t)layer * 48 * 512;
  float v = 0.f;
  if (n < 512) {
    const float* dw = dtw + (size_t)layer * 512 * 16 + n * 16;
#pragma unroll
    for (int r = 0; r < 16; ++r) v = fmaf(dw[r], xp[r * 512 + k], v);
  } else if (n < 544) {
    v = xp[(16 + (n - 512)) * 512 + k];
  }
  wc[((size_t)layer * 640 + n) * 512 + k] = f2bf(v);
}

// ---------------------------------------------------------------------------
// Causal depthwise conv (width 4) + bias + silu. xz bf16 (b,l,1024)[:,:512] -> xc bf16
// ---------------------------------------------------------------------------
__global__ __launch_bounds__(512)
void conv_silu(const u16* __restrict__ xz, const float* __restrict__ cw,
               const float* __restrict__ cb, u16* __restrict__ xc)
{
  const int b = blockIdx.x;          // 8
  const int l0 = blockIdx.y * 32;    // 32 chunks of 32
  const int d = threadIdx.x;         // 512

  const float w0 = cw[d * 4 + 0], w1 = cw[d * 4 + 1];
  const float w2 = cw[d * 4 + 2], w3 = cw[d * 4 + 3];
  const float bias = cb[d];

  const size_t base = ((size_t)b * L_SEQ) * 1024 + d;
  float xm3 = (l0 >= 3) ? bf2f(xz[base + (size_t)(l0 - 3) * 1024]) : 0.f;
  float xm2 = (l0 >= 2) ? bf2f(xz[base + (size_t)(l0 - 2) * 1024]) : 0.f;
  float xm1 = (l0 >= 1) ? bf2f(xz[base + (size_t)(l0 - 1) * 1024]) : 0.f;

#pragma unroll 4
  for (int i = 0; i < 32; ++i) {
    const int l = l0 + i;
    const float x0 = bf2f(xz[base + (size_t)l * 1024]);
    const float v = bias + w0 * xm3 + w1 * xm2 + w2 * xm1 + w3 * x0;
    xc[((size_t)b * L_SEQ + l) * 512 + d] = f2bf(silu_f(v));
    xm3 = xm2; xm2 = xm1; xm1 = x0;
  }
}

// ---------------------------------------------------------------------------
// Scan pass A: per-chunk aggregates. One thread per d; h[16]/p[16] in regs;
// B chunk staged in LDS (b128 broadcast reads). Ac = prod dA, Bc = local h.
// ---------------------------------------------------------------------------
__global__ __launch_bounds__(256)
void scan_passA(const float* __restrict__ xo, const u16* __restrict__ u,
                const float* __restrict__ Alog,
                float* __restrict__ Ac, float* __restrict__ Bc)
{
  const int b = blockIdx.x;
  const int d = blockIdx.y * 256 + threadIdx.x;
  const int c = blockIdx.z;
  const int t0 = c * TCHUNK;

  __shared__ float sB[TCHUNK][16];
#pragma unroll
  for (int r = 0; r < TCHUNK * 16; r += 256) {
    const int e = threadIdx.x + r;
    const int t = e >> 4, n = e & 15;
    sB[t][n] = xo[((size_t)b * L_SEQ + t0 + t) * 544 + 512 + n];
  }
  __syncthreads();

  float A[16], h[16], p[16];
  const float* al = Alog + d * 16;
#pragma unroll
  for (int n = 0; n < 16; ++n) { A[n] = -__expf(al[n]); h[n] = 0.f; p[n] = 1.f; }

#pragma unroll 2
  for (int t = 0; t < TCHUNK; ++t) {
    const size_t row = (size_t)b * L_SEQ + t0 + t;
    const float dtv = xo[row * 544 + d];
    const float uv  = bf2f(u[row * 512 + d]);
    const float cf  = dtv * uv;
    const f32x4* Bq = reinterpret_cast<const f32x4*>(&sB[t][0]);
#pragma unroll
    for (int q = 0; q < 4; ++q) {
      const f32x4 Bv = Bq[q];
#pragma unroll
      for (int k = 0; k < 4; ++k) {
        const int n = q * 4 + k;
        const float dA = __expf(dtv * A[n]);
        p[n] *= dA;
        h[n] = fmaf(dA, h[n], cf * Bv[k]);
      }
    }
  }

  float* ac = Ac + (((size_t)b * NCHUNK + c) * 512 + d) * 16;
  float* bc = Bc + (((size_t)b * NCHUNK + c) * 512 + d) * 16;
#pragma unroll
  for (int q = 0; q < 4; ++q) {
    f32x4 va, vb;
#pragma unroll
    for (int k = 0; k < 4; ++k) { va[k] = p[q * 4 + k]; vb[k] = h[q * 4 + k]; }
    reinterpret_cast<f32x4*>(ac)[q] = va;
    reinterpret_cast<f32x4*>(bc)[q] = vb;
  }
}

// ---------------------------------------------------------------------------
// Scan mid: exclusive-prefix chunk states. One thread per (b,d,n); 32-step
// serial chain over chunks. Hin[(b,c,d,n)] = state entering chunk c.
// ---------------------------------------------------------------------------
__global__ __launch_bounds__(256)
void scan_mid(const float* __restrict__ Ac, const float* __restrict__ Bc,
              float* __restrict__ Hin)
{
  const int gid = blockIdx.x * 256 + threadIdx.x;   // 65536 = 8*512*16
  const int b = gid >> 13;
  const int e = gid & 8191;                          // d*16 + n
  float h = 0.f;
  for (int c = 0; c < NCHUNK; ++c) {
    const size_t idx = ((size_t)(b * NCHUNK + c)) * 8192 + e;
    Hin[idx] = h;
    h = fmaf(Ac[idx], h, Bc[idx]);
  }
}

// ---------------------------------------------------------------------------
// Scan pass B: seeded full scan per chunk; writes yg = (y + u*D) * silu(z)
// as bf16 into the u buffer (read-before-write per element).
// ---------------------------------------------------------------------------
__global__ __launch_bounds__(256)
void scan_passB(const float* __restrict__ xo, const u16* __restrict__ u,
                const u16* __restrict__ xz,
                const float* __restrict__ Alog, const float* __restrict__ Dsk,
                const float* __restrict__ Hin, u16* __restrict__ yg)
{
  const int b = blockIdx.x;
  const int d = blockIdx.y * 256 + threadIdx.x;
  const int c = blockIdx.z;
  const int t0 = c * TCHUNK;

  __shared__ float sB[TCHUNK][16], sC[TCHUNK][16];
#pragma unroll
  for (int r = 0; r < TCHUNK * 16; r += 256) {
    const int e = threadIdx.x + r;
    const int t = e >> 4, n = e & 15;
    const size_t row = (size_t)b * L_SEQ + t0 + t;
    sB[t][n] = xo[row * 544 + 512 + n];
    sC[t][n] = xo[row * 544 + 528 + n];
  }
  __syncthreads();

  float A[16], h[16];
  const float* al = Alog + d * 16;
#pragma unroll
  for (int n = 0; n < 16; ++n) A[n] = -__expf(al[n]);

  const float* hp = Hin + (((size_t)b * NCHUNK + c) * 512 + d) * 16;
#pragma unroll
  for (int q = 0; q < 4; ++q) {
    const f32x4 v = reinterpret_cast<const f32x4*>(hp)[q];
#pragma unroll
    for (int k = 0; k < 4; ++k) h[q * 4 + k] = v[k];
  }

  const float Dv = Dsk[d];

#pragma unroll 2
  for (int t = 0; t < TCHUNK; ++t) {
    const size_t row = (size_t)b * L_SEQ + t0 + t;
    const float dtv = xo[row * 544 + d];
    const float uv  = bf2f(u[row * 512 + d]);
    const float zf  = bf2f(xz[row * 1024 + 512 + d]);
    const float cf  = dtv * uv;
    const f32x4* Bq = reinterpret_cast<const f32x4*>(&sB[t][0]);
    const f32x4* Cq = reinterpret_cast<const f32x4*>(&sC[t][0]);
    float s0 = 0.f, s1 = 0.f, s2 = 0.f, s3 = 0.f;
#pragma unroll
    for (int q = 0; q < 4; ++q) {
      const f32x4 Bv = Bq[q];
      const f32x4 Cv = Cq[q];
#pragma unroll
      for (int k = 0; k < 4; ++k) {
        const int n = q * 4 + k;
        const float dA = __expf(dtv * A[n]);
        h[n] = fmaf(dA, h[n], cf * Bv[k]);
      }
      s0 = fmaf(h[q * 4 + 0], Cv[0], s0);
      s1 = fmaf(h[q * 4 + 1], Cv[1], s1);
      s2 = fmaf(h[q * 4 + 2], Cv[2], s2);
      s3 = fmaf(h[q * 4 + 3], Cv[3], s3);
    }
    const float yv = fmaf(uv, Dv, (s0 + s1) + (s2 + s3));
    yg[row * 512 + d] = f2bf(yv * silu_f(zf));
  }
}

// ---------------------------------------------------------------------------
// Head: g = gelu_exact(h_last . p1w^T + p1b); out = g . p2w^T + p2b.  h bf16.
// ---------------------------------------------------------------------------
__global__ __launch_bounds__(256)
void head1(const u16* __restrict__ h, const float* __restrict__ p1w,
           const float* __restrict__ p1b, float* __restrict__ g)
{
  const int gid = blockIdx.x * 256 + threadIdx.x;  // 8192 = 1024 f x 8 b
  const int f = gid >> 3;
  const int b = gid & 7;
  const u16* hr = h + ((size_t)b * L_SEQ + (L_SEQ - 1)) * 256;
  const float* wr = p1w + (size_t)f * 256;
  float acc = 0.f;
#pragma unroll 4
  for (int k = 0; k < 256; k += 8) {
    u16x8 hv = *reinterpret_cast<const u16x8*>(hr + k);
    float4 w0 = *reinterpret_cast<const float4*>(wr + k);
    float4 w1 = *reinterpret_cast<const float4*>(wr + k + 4);
    acc = fmaf(bf2f(hv[0]), w0.x, acc); acc = fmaf(bf2f(hv[1]), w0.y, acc);
    acc = fmaf(bf2f(hv[2]), w0.z, acc); acc = fmaf(bf2f(hv[3]), w0.w, acc);
    acc = fmaf(bf2f(hv[4]), w1.x, acc); acc = fmaf(bf2f(hv[5]), w1.y, acc);
    acc = fmaf(bf2f(hv[6]), w1.z, acc); acc = fmaf(bf2f(hv[7]), w1.w, acc);
  }
  const float xv = acc + p1b[f];
  g[b * 1024 + f] = 0.5f * xv * (1.f + erff(xv * 0.70710678118654752f));
}

__global__ __launch_bounds__(256)
void head2(const float* __restrict__ g, const float* __restrict__ p2w,
           const float* __restrict__ p2b, float* __restrict__ out)
{
  const int b = blockIdx.x;
  const int tid = threadIdx.x;
  float acc = 0.f;
#pragma unroll
  for (int f = tid; f < 1024; f += 256) acc = fmaf(g[b * 1024 + f], p2w[f], acc);
  acc += __shfl_xor(acc, 1);
  acc += __shfl_xor(acc, 2);
  acc += __shfl_xor(acc, 4);
  acc += __shfl_xor(acc, 8);
  acc += __shfl_xor(acc, 16);
  acc += __shfl_xor(acc, 32);
  __shared__ float red[4];
  if ((tid & 63) == 0) red[tid >> 6] = acc;
  __syncthreads();
  if (tid == 0) out[b] = red[0] + red[1] + red[2] + red[3] + p2b[0];
}

// ---------------------------------------------------------------------------
extern "C" void kernel_launch(void* const* d_in, const int* in_sizes, int n_in,
                              void* d_out, int out_size, void* d_ws, size_t ws_size,
                              hipStream_t stream)
{
  const float* x    = (const float*)d_in[0];
  const float* in_w = (const float*)d_in[1];
  const float* in_b = (const float*)d_in[2];
  const float* ipw  = (const float*)d_in[3];
  const float* cw   = (const float*)d_in[4];
  const float* cb   = (const float*)d_in[5];
  const float* xpw  = (const float*)d_in[6];
  const float* dtw  = (const float*)d_in[7];
  const float* dtb  = (const float*)d_in[8];
  const float* Alog = (const float*)d_in[9];
  const float* Dsk  = (const float*)d_in[10];
  const float* opw  = (const float*)d_in[11];
  const float* p1w  = (const float*)d_in[12];
  const float* p1b  = (const float*)d_in[13];
  const float* p2w  = (const float*)d_in[14];
  const float* p2b  = (const float*)d_in[15];

  float* ws = (float*)d_ws;
  // layout (fp32-word offsets)
  u16*   h16  = (u16*)(ws);                 // 8192*256  bf16 -> 1,048,576 fw
  u16*   xz16 = (u16*)(ws + 1048576);       // 8192*1024 bf16 -> 4,194,304 fw
  u16*   xc16 = (u16*)(ws + 5242880);       // 8192*512  bf16 -> 2,097,152 fw
  float* xo   = ws + 7340032;               // 8192*544  f32  -> 4,456,448 fw
  u16*   wc16 = (u16*)(ws + 11796480);      // 2*640*512 bf16 ->   327,680 fw
  u16*   wbf  = (u16*)(ws + 12124160);      // casts:           528,384 fw
  float* g    = ws + 12652544;              // 8*1024 f32
  float* Ac   = ws + 12660736;              // 8*32*512*16 f32 -> 2,097,152 fw
  float* Bc   = ws + 14757888;              // 2,097,152 fw
  float* Hin  = ws + 16855040;              // 2,097,152 fw
  // end 18,952,192 fw ~= 75.8 MB

  // bf16 copies of fp32 operands: [x | in_w | ipw | opw]
  u16* x16   = wbf;                         // 262,144
  u16* inw16 = wbf + 262144;                // 8,192
  u16* ipw16 = wbf + 270336;                // 524,288
  u16* opw16 = wbf + 794624;                // 262,144

  cast_f2b<<<256, 256, 0, stream>>>(x, x16, 262144);
  cast_f2b<<<8, 256, 0, stream>>>(in_w, inw16, 8192);
  cast_f2b<<<512, 256, 0, stream>>>(ipw, ipw16, 524288);
  cast_f2b<<<256, 256, 0, stream>>>(opw, opw16, 262144);

  // combined x_proj/dt_proj weights (both layers), padded to 640 rows
  wprep<<<dim3(640, 2), 512, 0, stream>>>(dtw, xpw, wc16);

  // embed: h = x @ in_w^T + in_b  (M=8192,N=256,K=32) -> bf16
  gemm_async<64, 128, 1, 1><<<dim3(M_ROWS / 64, 2), 256, 0, stream>>>(
      x16, 32, inw16, 32, in_b, h16, 256, 256, 32);

  for (int layer = 0; layer < 2; ++layer) {
    const float* cw_l  = cw  + (size_t)layer * 512 * 4;
    const float* cb_l  = cb  + (size_t)layer * 512;
    const float* dtb_l = dtb + (size_t)layer * 512;
    const float* Al_l  = Alog + (size_t)layer * 512 * 16;
    const float* Dsk_l = Dsk + (size_t)layer * 512;
    const u16*   ipw_l = ipw16 + (size_t)layer * 1024 * 256;
    const u16*   opw_l = opw16 + (size_t)layer * 256 * 512;
    const u16*   wc_l  = wc16 + (size_t)layer * 640 * 512;

    // xz = h @ ipw^T  (N=1024,K=256) -> bf16
    gemm_async<128, 128, 0, 1><<<dim3(M_ROWS / 128, 8), 256, 0, stream>>>(
        h16, 256, ipw_l, 256, nullptr, xz16, 1024, 1024, 256);

    // xc = silu(causal_dwconv(xz[:, :512]) + cb) -> bf16
    conv_silu<<<dim3(8, 32), 512, 0, stream>>>(xz16, cw_l, cb_l, xc16);

    // xo = [softplus(xc@Wdt^T + dtb) | B | C]  (N=544 (pad 640), K=512) -> f32
    gemm_async<128, 128, 2, 0><<<dim3(M_ROWS / 128, 5), 256, 0, stream>>>(
        xc16, 512, wc_l, 512, dtb_l, xo, 544, 544, 512);

    // selective scan: passA (aggregates), mid (prefix states), passB (yg)
    scan_passA<<<dim3(8, 2, NCHUNK), 256, 0, stream>>>(
        xo, xc16, Al_l, Ac, Bc);
    scan_mid<<<256, 256, 0, stream>>>(Ac, Bc, Hin);
    scan_passB<<<dim3(8, 2, NCHUNK), 256, 0, stream>>>(
        xo, xc16, xz16, Al_l, Dsk_l, Hin, xc16);

    // h = yg @ opw^T  (N=256,K=512) -> bf16
    gemm_async<64, 128, 0, 1><<<dim3(M_ROWS / 64, 2), 256, 0, stream>>>(
        xc16, 512, opw_l, 512, nullptr, h16, 256, 256, 512);
  }

  head1<<<32, 256, 0, stream>>>(h16, p1w, p1b, g);
  head2<<<8, 256, 0, stream>>>(g, p2w, p2b, (float*)d_out);
}

// Round 7
// 374.123 us; speedup vs baseline: 2.5509x; 1.0308x over previous
//
#include <hip/hip_runtime.h>
#include <math.h>

// ---------------------------------------------------------------------------
// Mamba forward. Round 7:
//  - double-buffered async GEMM (issue k+1 global_load_lds before computing k;
//    one barrier/iter). R6 gemm was latency-bound: 1.25 blocks/CU, MfmaUtil 3.7%
//  - BM=64 tiles -> 2-4x more blocks/CU (in_proj 1024, combo 640, out_proj 512)
//  - merged prep kernel (4 casts + wprep); fused head (saves 5 launches)
// Shapes: B=8 L=1024 ENC=32 DM=256 DI=512 DS=16 DC=4 DTR=16 LAYERS=2 DFF=1024
// ---------------------------------------------------------------------------

static constexpr int L_SEQ = 1024;
static constexpr int M_ROWS = 8 * 1024;   // B*L
static constexpr int NCHUNK = 32;
static constexpr int TCHUNK = 32;         // L_SEQ / NCHUNK

typedef unsigned short u16;
typedef unsigned short u16x8 __attribute__((ext_vector_type(8)));
typedef unsigned short u16x4 __attribute__((ext_vector_type(4)));
typedef short bf16x8 __attribute__((ext_vector_type(8)));   // MFMA operand type
typedef float f32x4 __attribute__((ext_vector_type(4)));

__device__ __forceinline__ float silu_f(float x) { return x / (1.f + __expf(-x)); }
__device__ __forceinline__ float softplus_f(float x) {
  return (x > 20.f) ? x : log1pf(__expf(x));
}
__device__ __forceinline__ u16 f2bf(float f) {          // RNE fp32->bf16
  unsigned u = __builtin_bit_cast(unsigned, f);
  u += 0x7FFFu + ((u >> 16) & 1u);
  return (u16)(u >> 16);
}
__device__ __forceinline__ float bf2f(u16 v) {
  return __builtin_bit_cast(float, (unsigned)v << 16);
}

// async global->LDS, 16 B per lane; LDS dest = uniform base + lane*16
__device__ __forceinline__ void gll16(const u16* g, u16* l) {
  __builtin_amdgcn_global_load_lds(
      (const __attribute__((address_space(1))) void*)g,
      (__attribute__((address_space(3))) void*)l, 16, 0, 0);
}

// ---------------------------------------------------------------------------
// bf16 MFMA GEMM, double-buffered async staging.
// C[m,n] = epi( sum_k A[m,k]*W[n,k] ); A,W bf16 row-major (MxK / NxK).
// 256 thr = 4 waves (2x2), wave tile (BM/2)x(BN/2), MFMA 16x16x32, BK=32.
// LDS slot(lq,row) holds A[row][k0+lq*8..+8) (16 B); staged via global_load_lds
// (lane=row over 64-row windows). Frag b128 reads conflict-free.
// Loop: barrier (buf[cur] ready) -> issue k+1 into buf[cur^1] -> MFMA on cur.
// EPI: 0 none; 1 +bias; 2 combo (col<512 -> softplus(c+bias), else raw)
// OUTBF: 1 bf16 store, 0 fp32.  BM,BN mult of 64; W rows >= grid_y*BN.
// ---------------------------------------------------------------------------
template<int BM,int BN,int EPI,int OUTBF>
__global__ __launch_bounds__(256)
void gemm_db(const u16* __restrict__ A, int lda,
             const u16* __restrict__ W, int ldw,
             const float* __restrict__ bias,
             void* __restrict__ Cp, int ldc,
             int N, int K)
{
  constexpr int RWA = BM / 64, RWB = BN / 64;
  constexpr int NWA = 4 * RWA, NWB = 4 * RWB;
  constexpr int NWT = NWA + NWB;
  constexpr int TI = BM / 2 / 16;
  constexpr int TJ = BN / 2 / 16;

  __shared__ u16 As[2][BM * 32];
  __shared__ u16 Ws[2][BN * 32];

  const int tid = threadIdx.x;
  const int lane = tid & 63;
  const int wv = tid >> 6;
  const int wy = wv >> 1, wx = wv & 1;
  const int rb = wy * (BM / 2);
  const int cb = wx * (BN / 2);
  const int lr = lane & 15, lq = lane >> 4;
  const int bm = blockIdx.x * BM;
  const int bn = blockIdx.y * BN;

  f32x4 acc[TI][TJ];
#pragma unroll
  for (int i = 0; i < TI; ++i)
#pragma unroll
    for (int j = 0; j < TJ; ++j) acc[i][j] = (f32x4){0.f, 0.f, 0.f, 0.f};

  auto stage = [&](int k0, int buf) {
#pragma unroll
    for (int w = wv; w < NWT; w += 4) {
      if (w < NWA) {
        const int lqw = w / RWA, rh = w % RWA;
        gll16(A + (size_t)(bm + rh * 64 + lane) * lda + k0 + lqw * 8,
              &As[buf][(lqw * BM + rh * 64) * 8]);
      } else {
        const int w2 = w - NWA;
        const int lqw = w2 / RWB, rh = w2 % RWB;
        gll16(W + (size_t)(bn + rh * 64 + lane) * ldw + k0 + lqw * 8,
              &Ws[buf][(lqw * BN + rh * 64) * 8]);
      }
    }
  };

  stage(0, 0);
  int cur = 0;
  for (int k0 = 0; k0 < K; k0 += 32) {
    __syncthreads();                       // drains buf[cur] loads; frees buf[cur^1]
    if (k0 + 32 < K) stage(k0 + 32, cur ^ 1);

    bf16x8 af[TI], bf[TJ];
#pragma unroll
    for (int i = 0; i < TI; ++i)
      af[i] = *reinterpret_cast<const bf16x8*>(&As[cur][(lq * BM + rb + i * 16 + lr) * 8]);
#pragma unroll
    for (int j = 0; j < TJ; ++j)
      bf[j] = *reinterpret_cast<const bf16x8*>(&Ws[cur][(lq * BN + cb + j * 16 + lr) * 8]);
#pragma unroll
    for (int i = 0; i < TI; ++i)
#pragma unroll
      for (int j = 0; j < TJ; ++j)
        acc[i][j] = __builtin_amdgcn_mfma_f32_16x16x32_bf16(af[i], bf[j], acc[i][j], 0, 0, 0);
    cur ^= 1;
  }

#pragma unroll
  for (int i = 0; i < TI; ++i) {
#pragma unroll
    for (int j = 0; j < TJ; ++j) {
      const int col = bn + cb + j * 16 + lr;
      if (col >= N) continue;
#pragma unroll
      for (int r = 0; r < 4; ++r) {
        const int row = bm + rb + i * 16 + lq * 4 + r;
        float c = acc[i][j][r];
        if (EPI == 1) c += bias[col];
        if (EPI == 2) { if (col < 512) c = softplus_f(c + bias[col]); }
        if (OUTBF) ((u16*)Cp)[(size_t)row * ldc + col] = f2bf(c);
        else       ((float*)Cp)[(size_t)row * ldc + col] = c;
      }
    }
  }
}

// ---------------------------------------------------------------------------
// prep: merged fp32->bf16 casts (x, in_w, ipw, opw) + W_combo build.
// blocks 0..515: casts (512 thr x 4 elems). blocks 516..1795: wc rows.
// wc rows: 0..511 = dtw(512x16).xpw[0:16,:], 512..527 = B, 528..543 = C,
// 544..639 = 0 pad. bf16.
// ---------------------------------------------------------------------------
__global__ __launch_bounds__(512)
void prep(const float* __restrict__ x, const float* __restrict__ in_w,
          const float* __restrict__ ipw, const float* __restrict__ opw,
          const float* __restrict__ dtw, const float* __restrict__ xpw,
          u16* __restrict__ x16, u16* __restrict__ inw16,
          u16* __restrict__ ipw16, u16* __restrict__ opw16,
          u16* __restrict__ wc)
{
  const int blk = blockIdx.x;
  if (blk < 516) {
    const float* src; u16* dst; int base;
    if (blk < 128)      { src = x;    dst = x16;   base = blk; }
    else if (blk < 132) { src = in_w; dst = inw16; base = blk - 128; }
    else if (blk < 388) { src = ipw;  dst = ipw16; base = blk - 132; }
    else                { src = opw;  dst = opw16; base = blk - 388; }
    const int i = (base * 512 + threadIdx.x) * 4;
    float4 v = *reinterpret_cast<const float4*>(src + i);
    u16x4 o;
    o[0] = f2bf(v.x); o[1] = f2bf(v.y); o[2] = f2bf(v.z); o[3] = f2bf(v.w);
    *reinterpret_cast<u16x4*>(dst + i) = o;
  } else {
    const int idx = blk - 516;
    const int layer = idx / 640;
    const int n = idx % 640;
    const int k = threadIdx.x;
    const float* xp = xpw + (size_t)layer * 48 * 512;
    float v = 0.f;
    if (n < 512) {
      const float* dw = dtw + (size_t)layer * 512 * 16 + n * 16;
#pragma unroll
      for (int r = 0; r < 16; ++r) v = fmaf(dw[r], xp[r * 512 + k], v);
    } else if (n < 544) {
      v = xp[(16 + (n - 512)) * 512 + k];
    }
    wc[((size_t)layer * 640 + n) * 512 + k] = f2bf(v);
  }
}

// ---------------------------------------------------------------------------
// Causal depthwise conv (width 4) + bias + silu. xz bf16 (b,l,1024)[:,:512] -> xc bf16
// ---------------------------------------------------------------------------
__global__ __launch_bounds__(512)
void conv_silu(const u16* __restrict__ xz, const float* __restrict__ cw,
               const float* __restrict__ cb, u16* __restrict__ xc)
{
  const int b = blockIdx.x;          // 8
  const int l0 = blockIdx.y * 32;    // 32 chunks of 32
  const int d = threadIdx.x;         // 512

  const float w0 = cw[d * 4 + 0], w1 = cw[d * 4 + 1];
  const float w2 = cw[d * 4 + 2], w3 = cw[d * 4 + 3];
  const float bias = cb[d];

  const size_t base = ((size_t)b * L_SEQ) * 1024 + d;
  float xm3 = (l0 >= 3) ? bf2f(xz[base + (size_t)(l0 - 3) * 1024]) : 0.f;
  float xm2 = (l0 >= 2) ? bf2f(xz[base + (size_t)(l0 - 2) * 1024]) : 0.f;
  float xm1 = (l0 >= 1) ? bf2f(xz[base + (size_t)(l0 - 1) * 1024]) : 0.f;

#pragma unroll 4
  for (int i = 0; i < 32; ++i) {
    const int l = l0 + i;
    const float x0 = bf2f(xz[base + (size_t)l * 1024]);
    const float v = bias + w0 * xm3 + w1 * xm2 + w2 * xm1 + w3 * x0;
    xc[((size_t)b * L_SEQ + l) * 512 + d] = f2bf(silu_f(v));
    xm3 = xm2; xm2 = xm1; xm1 = x0;
  }
}

// ---------------------------------------------------------------------------
// Scan pass A: per-chunk aggregates. One thread per d; h[16]/p[16] in regs;
// B chunk staged in LDS (b128 broadcast reads). Ac = prod dA, Bc = local h.
// ---------------------------------------------------------------------------
__global__ __launch_bounds__(256)
void scan_passA(const float* __restrict__ xo, const u16* __restrict__ u,
                const float* __restrict__ Alog,
                float* __restrict__ Ac, float* __restrict__ Bc)
{
  const int b = blockIdx.x;
  const int d = blockIdx.y * 256 + threadIdx.x;
  const int c = blockIdx.z;
  const int t0 = c * TCHUNK;

  __shared__ float sB[TCHUNK][16];
#pragma unroll
  for (int r = 0; r < TCHUNK * 16; r += 256) {
    const int e = threadIdx.x + r;
    const int t = e >> 4, n = e & 15;
    sB[t][n] = xo[((size_t)b * L_SEQ + t0 + t) * 544 + 512 + n];
  }
  __syncthreads();

  float A[16], h[16], p[16];
  const float* al = Alog + d * 16;
#pragma unroll
  for (int n = 0; n < 16; ++n) { A[n] = -__expf(al[n]); h[n] = 0.f; p[n] = 1.f; }

#pragma unroll 2
  for (int t = 0; t < TCHUNK; ++t) {
    const size_t row = (size_t)b * L_SEQ + t0 + t;
    const float dtv = xo[row * 544 + d];
    const float uv  = bf2f(u[row * 512 + d]);
    const float cf  = dtv * uv;
    const f32x4* Bq = reinterpret_cast<const f32x4*>(&sB[t][0]);
#pragma unroll
    for (int q = 0; q < 4; ++q) {
      const f32x4 Bv = Bq[q];
#pragma unroll
      for (int k = 0; k < 4; ++k) {
        const int n = q * 4 + k;
        const float dA = __expf(dtv * A[n]);
        p[n] *= dA;
        h[n] = fmaf(dA, h[n], cf * Bv[k]);
      }
    }
  }

  float* ac = Ac + (((size_t)b * NCHUNK + c) * 512 + d) * 16;
  float* bc = Bc + (((size_t)b * NCHUNK + c) * 512 + d) * 16;
#pragma unroll
  for (int q = 0; q < 4; ++q) {
    f32x4 va, vb;
#pragma unroll
    for (int k = 0; k < 4; ++k) { va[k] = p[q * 4 + k]; vb[k] = h[q * 4 + k]; }
    reinterpret_cast<f32x4*>(ac)[q] = va;
    reinterpret_cast<f32x4*>(bc)[q] = vb;
  }
}

// ---------------------------------------------------------------------------
// Scan mid: exclusive-prefix chunk states. One thread per (b,d,n).
// ---------------------------------------------------------------------------
__global__ __launch_bounds__(256)
void scan_mid(const float* __restrict__ Ac, const float* __restrict__ Bc,
              float* __restrict__ Hin)
{
  const int gid = blockIdx.x * 256 + threadIdx.x;   // 65536 = 8*512*16
  const int b = gid >> 13;
  const int e = gid & 8191;                          // d*16 + n
  float h = 0.f;
  for (int c = 0; c < NCHUNK; ++c) {
    const size_t idx = ((size_t)(b * NCHUNK + c)) * 8192 + e;
    Hin[idx] = h;
    h = fmaf(Ac[idx], h, Bc[idx]);
  }
}

// ---------------------------------------------------------------------------
// Scan pass B: seeded full scan per chunk; writes yg = (y + u*D) * silu(z)
// as bf16 into the u buffer (read-before-write per element).
// ---------------------------------------------------------------------------
__global__ __launch_bounds__(256)
void scan_passB(const float* __restrict__ xo, const u16* __restrict__ u,
                const u16* __restrict__ xz,
                const float* __restrict__ Alog, const float* __restrict__ Dsk,
                const float* __restrict__ Hin, u16* __restrict__ yg)
{
  const int b = blockIdx.x;
  const int d = blockIdx.y * 256 + threadIdx.x;
  const int c = blockIdx.z;
  const int t0 = c * TCHUNK;

  __shared__ float sB[TCHUNK][16], sC[TCHUNK][16];
#pragma unroll
  for (int r = 0; r < TCHUNK * 16; r += 256) {
    const int e = threadIdx.x + r;
    const int t = e >> 4, n = e & 15;
    const size_t row = (size_t)b * L_SEQ + t0 + t;
    sB[t][n] = xo[row * 544 + 512 + n];
    sC[t][n] = xo[row * 544 + 528 + n];
  }
  __syncthreads();

  float A[16], h[16];
  const float* al = Alog + d * 16;
#pragma unroll
  for (int n = 0; n < 16; ++n) A[n] = -__expf(al[n]);

  const float* hp = Hin + (((size_t)b * NCHUNK + c) * 512 + d) * 16;
#pragma unroll
  for (int q = 0; q < 4; ++q) {
    const f32x4 v = reinterpret_cast<const f32x4*>(hp)[q];
#pragma unroll
    for (int k = 0; k < 4; ++k) h[q * 4 + k] = v[k];
  }

  const float Dv = Dsk[d];

#pragma unroll 2
  for (int t = 0; t < TCHUNK; ++t) {
    const size_t row = (size_t)b * L_SEQ + t0 + t;
    const float dtv = xo[row * 544 + d];
    const float uv  = bf2f(u[row * 512 + d]);
    const float zf  = bf2f(xz[row * 1024 + 512 + d]);
    const float cf  = dtv * uv;
    const f32x4* Bq = reinterpret_cast<const f32x4*>(&sB[t][0]);
    const f32x4* Cq = reinterpret_cast<const f32x4*>(&sC[t][0]);
    float s0 = 0.f, s1 = 0.f, s2 = 0.f, s3 = 0.f;
#pragma unroll
    for (int q = 0; q < 4; ++q) {
      const f32x4 Bv = Bq[q];
      const f32x4 Cv = Cq[q];
#pragma unroll
      for (int k = 0; k < 4; ++k) {
        const int n = q * 4 + k;
        const float dA = __expf(dtv * A[n]);
        h[n] = fmaf(dA, h[n], cf * Bv[k]);
      }
      s0 = fmaf(h[q * 4 + 0], Cv[0], s0);
      s1 = fmaf(h[q * 4 + 1], Cv[1], s1);
      s2 = fmaf(h[q * 4 + 2], Cv[2], s2);
      s3 = fmaf(h[q * 4 + 3], Cv[3], s3);
    }
    const float yv = fmaf(uv, Dv, (s0 + s1) + (s2 + s3));
    yg[row * 512 + d] = f2bf(yv * silu_f(zf));
  }
}

// ---------------------------------------------------------------------------
// Fused head: one block per batch. g[f] = gelu(h_last.p1w[f]+p1b[f]);
// out[b] = sum_f g[f]*p2w[f] + p2b.
// ---------------------------------------------------------------------------
__global__ __launch_bounds__(1024)
void head(const u16* __restrict__ h, const float* __restrict__ p1w,
          const float* __restrict__ p1b, const float* __restrict__ p2w,
          const float* __restrict__ p2b, float* __restrict__ out)
{
  const int b = blockIdx.x;
  const int f = threadIdx.x;

  __shared__ float hl[256];
  if (f < 256) hl[f] = bf2f(h[((size_t)b * L_SEQ + (L_SEQ - 1)) * 256 + f]);
  __syncthreads();

  const float* wr = p1w + (size_t)f * 256;
  float acc = 0.f;
#pragma unroll 8
  for (int k = 0; k < 256; k += 4) {
    float4 wv = *reinterpret_cast<const float4*>(wr + k);
    acc = fmaf(hl[k + 0], wv.x, acc);
    acc = fmaf(hl[k + 1], wv.y, acc);
    acc = fmaf(hl[k + 2], wv.z, acc);
    acc = fmaf(hl[k + 3], wv.w, acc);
  }
  const float xv = acc + p1b[f];
  const float gg = 0.5f * xv * (1.f + erff(xv * 0.70710678118654752f));
  float s = gg * p2w[f];

  s += __shfl_xor(s, 1);
  s += __shfl_xor(s, 2);
  s += __shfl_xor(s, 4);
  s += __shfl_xor(s, 8);
  s += __shfl_xor(s, 16);
  s += __shfl_xor(s, 32);
  __shared__ float red[16];
  if ((f & 63) == 0) red[f >> 6] = s;
  __syncthreads();
  if (f == 0) {
    float t = 0.f;
#pragma unroll
    for (int i = 0; i < 16; ++i) t += red[i];
    out[b] = t + p2b[0];
  }
}

// ---------------------------------------------------------------------------
extern "C" void kernel_launch(void* const* d_in, const int* in_sizes, int n_in,
                              void* d_out, int out_size, void* d_ws, size_t ws_size,
                              hipStream_t stream)
{
  const float* x    = (const float*)d_in[0];
  const float* in_w = (const float*)d_in[1];
  const float* in_b = (const float*)d_in[2];
  const float* ipw  = (const float*)d_in[3];
  const float* cw   = (const float*)d_in[4];
  const float* cb   = (const float*)d_in[5];
  const float* xpw  = (const float*)d_in[6];
  const float* dtw  = (const float*)d_in[7];
  const float* dtb  = (const float*)d_in[8];
  const float* Alog = (const float*)d_in[9];
  const float* Dsk  = (const float*)d_in[10];
  const float* opw  = (const float*)d_in[11];
  const float* p1w  = (const float*)d_in[12];
  const float* p1b  = (const float*)d_in[13];
  const float* p2w  = (const float*)d_in[14];
  const float* p2b  = (const float*)d_in[15];

  float* ws = (float*)d_ws;
  // layout (fp32-word offsets)
  u16*   h16  = (u16*)(ws);                 // 8192*256  bf16 -> 1,048,576 fw
  u16*   xz16 = (u16*)(ws + 1048576);       // 8192*1024 bf16 -> 4,194,304 fw
  u16*   xc16 = (u16*)(ws + 5242880);       // 8192*512  bf16 -> 2,097,152 fw
  float* xo   = ws + 7340032;               // 8192*544  f32  -> 4,456,448 fw
  u16*   wc16 = (u16*)(ws + 11796480);      // 2*640*512 bf16 ->   327,680 fw
  u16*   wbf  = (u16*)(ws + 12124160);      // casts:           528,384 fw
  float* Ac   = ws + 12660736;              // 8*32*512*16 f32 -> 2,097,152 fw
  float* Bc   = ws + 14757888;              // 2,097,152 fw
  float* Hin  = ws + 16855040;              // 2,097,152 fw
  // end 18,952,192 fw ~= 75.8 MB

  // bf16 copies of fp32 operands: [x | in_w | ipw | opw]
  u16* x16   = wbf;                         // 262,144
  u16* inw16 = wbf + 262144;                // 8,192
  u16* ipw16 = wbf + 270336;                // 524,288
  u16* opw16 = wbf + 794624;                // 262,144

  // merged casts + W_combo build
  prep<<<1796, 512, 0, stream>>>(x, in_w, ipw, opw, dtw, xpw,
                                 x16, inw16, ipw16, opw16, wc16);

  // embed: h = x @ in_w^T + in_b  (M=8192,N=256,K=32) -> bf16
  gemm_db<64, 128, 1, 1><<<dim3(M_ROWS / 64, 2), 256, 0, stream>>>(
      x16, 32, inw16, 32, in_b, h16, 256, 256, 32);

  for (int layer = 0; layer < 2; ++layer) {
    const float* cw_l  = cw  + (size_t)layer * 512 * 4;
    const float* cb_l  = cb  + (size_t)layer * 512;
    const float* dtb_l = dtb + (size_t)layer * 512;
    const float* Al_l  = Alog + (size_t)layer * 512 * 16;
    const float* Dsk_l = Dsk + (size_t)layer * 512;
    const u16*   ipw_l = ipw16 + (size_t)layer * 1024 * 256;
    const u16*   opw_l = opw16 + (size_t)layer * 256 * 512;
    const u16*   wc_l  = wc16 + (size_t)layer * 640 * 512;

    // xz = h @ ipw^T  (N=1024,K=256) -> bf16   (1024 blocks, 4/CU)
    gemm_db<64, 128, 0, 1><<<dim3(M_ROWS / 64, 8), 256, 0, stream>>>(
        h16, 256, ipw_l, 256, nullptr, xz16, 1024, 1024, 256);

    // xc = silu(causal_dwconv(xz[:, :512]) + cb) -> bf16
    conv_silu<<<dim3(8, 32), 512, 0, stream>>>(xz16, cw_l, cb_l, xc16);

    // xo = [softplus(xc@Wdt^T + dtb) | B | C]  (N=544 pad 640, K=512) -> f32
    gemm_db<64, 128, 2, 0><<<dim3(M_ROWS / 64, 5), 256, 0, stream>>>(
        xc16, 512, wc_l, 512, dtb_l, xo, 544, 544, 512);

    // selective scan: passA (aggregates), mid (prefix states), passB (yg)
    scan_passA<<<dim3(8, 2, NCHUNK), 256, 0, stream>>>(
        xo, xc16, Al_l, Ac, Bc);
    scan_mid<<<256, 256, 0, stream>>>(Ac, Bc, Hin);
    scan_passB<<<dim3(8, 2, NCHUNK), 256, 0, stream>>>(
        xo, xc16, xz16, Al_l, Dsk_l, Hin, xc16);

    // h = yg @ opw^T  (N=256,K=512) -> bf16   (512 blocks, 2/CU)
    gemm_db<64, 64, 0, 1><<<dim3(M_ROWS / 64, 4), 256, 0, stream>>>(
        xc16, 512, opw_l, 512, nullptr, h16, 256, 256, 512);
  }

  head<<<8, 1024, 0, stream>>>(h16, p1w, p1b, p2w, p2b, (float*)d_out);
}